// Round 5
// baseline (209.119 us; speedup 1.0000x reference)
//
#include <hip/hip_runtime.h>
#include <hip/hip_cooperative_groups.h>
#include <stdint.h>

namespace cg = cooperative_groups;

#define NIMG 32
#define WID 384
#define HW 147456            // 384*384
#define TOPK 1000
#define KPAD 1024
#define NBINS 512
#define BIN_SCALEF 512.0f
#define NSEG 8               // sub-segments per image
#define SEGN (NIMG * NSEG)   // 256 segments == cooperative grid size (1 block/CU at ~96KB LDS)
#define SEGV 4608            // float4 per segment = HW/NSEG/4
#define SEGCAP 256           // per-seg count ~184 +/- 13.5 (+5.3 sigma); overflow -> exact fallback
#define CANDCAP 2048
#define THRESH 0.05f
#define PREF_C 0.99f         // count(s>0.99) ~ 1475 +/- 38 per image; runtime-checked, exact fallback
#define NMS_T 0.4f
#define FINEBINS 256         // fine histogram bins over (0.99, 1.0] for rank placement

typedef unsigned long long u64;
typedef unsigned int u32;

// ---------------- workspace layout (bytes); total 1.58 MB < 1.97 MB proven in Round 0 ----------------
#define PCNT_OFF 0                                   // 256 u32
#define PCAND_OFF 4096                               // 256*256 u64 = 524288 -> ends 528384
#define PBOX_OFF 528384                              // 256*256 float4 = 1048576 -> ends 1576960

// ---------- numerics helpers (fp-contraction-proof, matches numpy f32) ----------
__device__ __forceinline__ float area_of(float x0, float y0, float x1, float y1) {
  float a = fmaxf(x1 - x0, 0.0f) * fmaxf(y1 - y0, 0.0f);
  asm volatile("" : "+v"(a));
  return a;
}

__device__ __forceinline__ bool iou_gt(float ax0, float ay0, float ax1, float ay1, float aa,
                                       float bx0, float by0, float bx1, float by1, float ba) {
  float ix1 = fmaxf(ax0, bx0);
  float iy1 = fmaxf(ay0, by0);
  float ix2 = fminf(ax1, bx1);
  float iy2 = fminf(ay1, by1);
  float iw = fmaxf(ix2 - ix1, 0.0f);
  float ih = fmaxf(iy2 - iy1, 0.0f);
  float inter = iw * ih;
  asm volatile("" : "+v"(inter));
  float uni = fmaxf(aa + ba - inter, 1e-9f);
  return (inter / uni) > NMS_T;
}

__device__ __forceinline__ u64 shflxor64(u64 v, int m) {
  int lo = __shfl_xor((int)(u32)v, m, 64);
  int hi = __shfl_xor((int)(u32)(v >> 32), m, 64);
  return ((u64)(u32)hi << 32) | (u32)lo;
}

__device__ __forceinline__ u64 make_key(float s, u32 idx) {
  u32 ord = __float_as_uint(s) | 0x80000000u;   // s > 0 always here
  return ((u64)ord << 32) | (u32)(~idx);        // desc score, ties asc index (lax.top_k)
}

__device__ __forceinline__ float score_of(u64 key) {
  return __uint_as_float((u32)(key >> 32) & 0x7FFFFFFFu);
}

__device__ __forceinline__ int bin_of(float s) {
  int b = (int)(s * BIN_SCALEF);
  return b < 0 ? 0 : (b > NBINS - 1 ? NBINS - 1 : b);
}

// fine bin over (0.99, 1.0]; monotone non-decreasing in s (f32 sub + mul + trunc are monotone)
__device__ __forceinline__ int finebin(u64 key) {
  float s = score_of(key);
  int b = (int)((s - 0.99f) * 25600.0f);
  return b < 0 ? 0 : (b > FINEBINS - 1 ? FINEBINS - 1 : b);
}

// ---------- phase A: prefilter collect + decode (256 blocks x 1024 threads) ----------
__device__ void phaseA(const float* __restrict__ cls, const float* __restrict__ reg,
                       u32* __restrict__ pcnt, u64* __restrict__ pcand,
                       float4* __restrict__ pbox, int bid) {
  __shared__ u64 lbuf[SEGCAP];
  __shared__ u32 lcnt;
  const int tid = threadIdx.x;
  const int lane = tid & 63;
  if (tid == 0) lcnt = 0;
  __syncthreads();

  const int n = bid >> 3;      // image
  const int sub = bid & 7;     // sub-segment
  const float4* src = (const float4*)(cls + (size_t)n * HW) + sub * SEGV;
  float4 A[5];
#pragma unroll
  for (int v = 0; v < 4; v++) A[v] = src[tid + v * 1024];
  A[4] = (tid < 512) ? src[tid + 4096] : make_float4(0.f, 0.f, 0.f, 0.f);  // zeros never pass PREF_C

  const u64 ltmask = (1ull << lane) - 1ull;
#pragma unroll
  for (int v = 0; v < 5; v++) {
    float ss[4] = {A[v].x, A[v].y, A[v].z, A[v].w};
#pragma unroll
    for (int c = 0; c < 4; c++) {
      float s = ss[c];
      bool pc = s > PREF_C;
      u64 m = __ballot(pc);
      if (m) {
        int ldr = __ffsll(m) - 1;
        u32 wb = 0;
        if (lane == ldr) wb = atomicAdd(&lcnt, (u32)__popcll(m));   // LDS atomic only
        wb = (u32)__shfl((int)wb, ldr, 64);
        if (pc) {
          u32 pos = wb + (u32)__popcll(m & ltmask);
          if (pos < SEGCAP) lbuf[pos] = make_key(s, (u32)((sub * SEGV + tid + v * 1024) * 4 + c));
        }
      }
    }
  }
  __syncthreads();
  if (tid == 0) pcnt[bid] = (lcnt > SEGCAP) ? 0xFFFFFFFFu : lcnt;
  u32 c = lcnt < SEGCAP ? lcnt : (u32)SEGCAP;
  // decode boxes here: idx local to this block's 18K range; 256 blocks x 1024 threads of MLP
  const float* rb = reg + (size_t)n * 4 * HW;
  u64* pk = pcand + (size_t)bid * SEGCAP;
  float4* pb = pbox + (size_t)bid * SEGCAP;
  for (u32 i = tid; i < c; i += 1024) {
    u64 key = lbuf[i];
    u32 idx = ~(u32)(key & 0xFFFFFFFFull);
    int iy = (int)idx / WID;
    int ix = (int)idx - iy * WID;
    float xx = (float)ix * 4.0f;
    float yy = (float)iy * 4.0f;
    float r0 = rb[idx];
    float r1 = rb[HW + idx];
    float r2 = rb[2 * HW + idx];
    float r3 = rb[3 * HW + idx];
    float4 box;
    box.y = yy - r0; box.z = xx + r1; box.w = yy + r2; box.x = xx - r3;
    pk[i] = key;
    pb[i] = box;
  }
}

// reg-chain bitonic levels for stage k (jstart <= 64, via shuffles, no barriers) -- fallback only
#define REGCHAIN(K, JSTART) do {                                            \
    const bool desc_ = ((tid & ((K) >> 1)) == 0);                           \
    for (int j_ = (JSTART); j_ >= 2; j_ >>= 1) {                            \
      int h_ = j_ >> 1;                                                     \
      bool low_ = (tid & h_) == 0;                                          \
      u64 p0_ = shflxor64(e0, h_), p1_ = shflxor64(e1, h_);                 \
      bool tm_ = (low_ == desc_);                                           \
      e0 = tm_ ? (e0 > p0_ ? e0 : p0_) : (e0 < p0_ ? e0 : p0_);             \
      e1 = tm_ ? (e1 > p1_ ? e1 : p1_) : (e1 < p1_ ? e1 : p1_);             \
    }                                                                       \
    { u64 lo_ = e0 < e1 ? e0 : e1, hi_ = e0 < e1 ? e1 : e0;                 \
      e0 = desc_ ? hi_ : lo_; e1 = desc_ ? lo_ : hi_; }                     \
  } while (0)

// ---------- phase B: gather + rank-place + valid-compact NMS + output (one block per image) ----------
// Rank placement: fast-path scores all lie in (0.99, 1]; a 256-bin monotone histogram + prefix gives
// rank = C - binstart[b+1] + #{same-bin keys > k} (full u64 compare). Keys distinct (distinct idx),
// binning monotone in score, bins tile rank-space contiguously => exact total order == bitonic order.
// Exactness of valid-compact NMS: invalid boxes (w<0 / h<0 / s<=0.05 / rank>=1000) have keep=false
// from the start in the reference and can never suppress (clipped area/inter = 0 -> iou = 0 <= 0.4).
__device__ void phaseB(const float* __restrict__ cls, const float* __restrict__ reg,
                       const u32* __restrict__ pcnt, const u64* __restrict__ pcand,
                       const float4* __restrict__ pbox, float* __restrict__ out, int n) {
  // ---- manually-carved LDS arena: phase1 (ranking) overlaid with phase2 (NMS) ----
  __shared__ __align__(16) unsigned char smem[90112];
  u64*    CKEY   = (u64*)smem;                    // [2048] keys; also fallback bitonic buffer (16KB)
  float4* CBOX   = (float4*)(smem + 16384);       // [2048] boxes (32KB) -> 49152
  u32*    BINNED = (u32*)(smem + 49152);          // [2048] bin-grouped candidate ids (8KB) -> 57344
  u64*    RKEY   = (u64*)(smem + 57344);          // [1024] rank-placed keys (8KB) -> 65536
  float4* RBOX   = (float4*)(smem + 65536);       // [1024] rank-placed boxes (16KB) -> 81920
  // phase2 overlay (all phase1 arrays dead before these are written; barriers enforce handoff)
  float* vx    = (float*)smem;                    // [1024] SoA boxes: conflict-free stride-4B reads
  float* vy    = (float*)(smem + 4096);
  float* vz    = (float*)(smem + 8192);
  float* vw    = (float*)(smem + 12288);
  float* varea = (float*)(smem + 16384);          // -> 20480
  u64*   mlds  = (u64*)(smem + 20480);            // [136*64] suppression triangle (68KB) -> 90112

  __shared__ u32 BINSTART[FINEBINS + 1];
  __shared__ u32 HIST[FINEBINS];       // histogram, then reused as per-bin fill counters
  __shared__ u32 scnt[NSEG];
  __shared__ u32 soff[NSEG];
  __shared__ u32 bs[NBINS];            // fallback only
  __shared__ u32 stmp[64];
  __shared__ int stbin;
  __shared__ u32 sflag, sfc;
  __shared__ int sC;
  __shared__ u32 wcnt[16], woff[16];
  __shared__ int pc[136], pk[136];
  __shared__ int sV, snch, snp;
  __shared__ u64 keepsh[16], srem[16];

  const int tid = threadIdx.x;
  const int lane = tid & 63;
  const int w = tid >> 6;
  const u64 ltmask = (1ull << lane) - 1ull;

  // ---- init ----
  if (tid < NSEG) scnt[tid] = pcnt[n * NSEG + tid];
  RKEY[tid] = 0ull;
  if (tid < FINEBINS) HIST[tid] = 0;
  if (tid == 0) sfc = 0;
  __syncthreads();
  if (tid == 0) {
    u32 f = 0, off = 0;
    for (int s = 0; s < NSEG; s++) {
      u32 c = scnt[s];
      if (c == 0xFFFFFFFFu) { f = 1; c = 0; }
      soff[s] = off; off += c;
    }
    if (off < TOPK || off > CANDCAP) f = 1;   // prefilter unusable -> exact fallback
    sflag = f; sC = (int)off;
  }
  __syncthreads();

  u64 key; float4 b;

  if (sflag == 0) {
    const int C = sC;
    // ---- coalesced gather (128 threads per segment; 2 iterations at c~184) ----
    {
      int s = tid >> 7;
      u32 c = scnt[s], o = soff[s];
      const u64* srck = pcand + (size_t)(n * NSEG + s) * SEGCAP;
      const float4* srcb = pbox + (size_t)(n * NSEG + s) * SEGCAP;
      for (u32 i = (u32)(tid & 127); i < c; i += 128) {
        CKEY[o + i] = srck[i];
        CBOX[o + i] = srcb[i];
      }
    }
    __syncthreads();
    // ---- fine histogram ----
    for (int i = tid; i < C; i += 1024) atomicAdd(&HIST[finebin(CKEY[i])], 1u);
    __syncthreads();
    // ---- prefix (wave 0; 4 bins/lane) + zero HIST for reuse as fill counters ----
    if (tid < 64) {
      u32 h0 = HIST[lane * 4 + 0], h1 = HIST[lane * 4 + 1];
      u32 h2 = HIST[lane * 4 + 2], h3 = HIST[lane * 4 + 3];
      u32 t = h0 + h1 + h2 + h3;
      u32 incl = t;
#pragma unroll
      for (int d = 1; d < 64; d <<= 1) {
        u32 v = (u32)__shfl_up((int)incl, d, 64);
        if (lane >= d) incl += v;
      }
      u32 base = incl - t;
      BINSTART[lane * 4 + 0] = base;
      BINSTART[lane * 4 + 1] = base + h0;
      BINSTART[lane * 4 + 2] = base + h0 + h1;
      BINSTART[lane * 4 + 3] = base + h0 + h1 + h2;
      if (lane == 63) BINSTART[FINEBINS] = incl;    // == C
      HIST[lane * 4 + 0] = 0; HIST[lane * 4 + 1] = 0;
      HIST[lane * 4 + 2] = 0; HIST[lane * 4 + 3] = 0;
    }
    __syncthreads();
    // ---- scatter candidate ids into bin groups ----
    for (int i = tid; i < C; i += 1024) {
      int bb = finebin(CKEY[i]);
      u32 slot = atomicAdd(&HIST[bb], 1u);
      BINNED[BINSTART[bb] + slot] = (u32)i;
    }
    __syncthreads();
    // ---- exact rank + direct placement (top-1024 only; ~6 in-bin compares avg) ----
    for (int i = tid; i < C; i += 1024) {
      u64 k = CKEY[i];
      int bb = finebin(k);
      u32 s0 = BINSTART[bb], s1 = BINSTART[bb + 1];
      u32 g = 0;
      for (u32 j = s0; j < s1; j++) {
        u32 cj = BINNED[j];
        if (CKEY[cj] > k) g++;
      }
      u32 rank = (u32)C - s1 + g;
      if (rank < KPAD) { RKEY[rank] = k; RBOX[rank] = CBOX[i]; }
    }
    __syncthreads();
    key = RKEY[tid];
    b = (key != 0ull) ? RBOX[tid] : make_float4(0.f, 0.f, 0.f, 0.f);
  } else {
    // ---- exact fallback (dead path for bench input): histogram cutoff + collect + bitonic + decode
    for (int i = tid; i < NBINS; i += 1024) bs[i] = 0;
    CKEY[tid] = 0ull; CKEY[tid + 1024] = 0ull;
    __syncthreads();
    const float* ci = cls + (size_t)n * HW;
    for (int base = 0; base < HW; base += 1024) {
      float s = ci[base + tid];
      if (s > THRESH) atomicAdd(&bs[bin_of(s)], 1u);
    }
    __syncthreads();
    if (tid < 64) {
      u32 cs = 0;
#pragma unroll
      for (int k2 = 0; k2 < 8; k2++) cs += bs[lane * 8 + k2];
      u32 s = cs;
#pragma unroll
      for (int d = 1; d < 64; d <<= 1) {
        u32 v = (u32)__shfl_down((int)s, d, 64);
        if (lane + d < 64) s += v;
      }
      stmp[lane] = s;
      u64 mask = __ballot(s >= TOPK);
      if (lane == 0) {
        int t = 0;
        if (mask) {
          int L = 63 - __clzll(mask);
          u32 acc = (L < 63) ? stmp[L + 1] : 0;
          for (int bb = L * 8 + 7; bb >= L * 8; bb--) {
            acc += bs[bb];
            if (acc >= TOPK) { t = bb; break; }
          }
        }
        stbin = t;
      }
    }
    __syncthreads();
    const int t = stbin;
    for (int base = 0; base < HW; base += 1024) {
      int i = base + tid;
      float s = ci[i];
      bool p = (s > THRESH) && (bin_of(s) >= t);
      u64 m = __ballot(p);
      if (m) {
        int ldr = __ffsll(m) - 1;
        u32 wb = 0;
        if (lane == ldr) wb = atomicAdd(&sfc, (u32)__popcll(m));
        wb = (u32)__shfl((int)wb, ldr, 64);
        if (p) { u32 pos = wb + (u32)__popcll(m & ltmask); if (pos < CANDCAP) CKEY[pos] = make_key(s, (u32)i); }
      }
    }
    __syncthreads();
    // hybrid bitonic sort (2048 keys, 2/thread; shfl for j<=64, LDS for j>=128)
    {
      u64 e0 = CKEY[2 * tid], e1 = CKEY[2 * tid + 1];
      REGCHAIN(2, 1); REGCHAIN(4, 2); REGCHAIN(8, 4); REGCHAIN(16, 8);
      REGCHAIN(32, 16); REGCHAIN(64, 32); REGCHAIN(128, 64);
      for (int k = 256; k <= CANDCAP; k <<= 1) {
        CKEY[2 * tid] = e0; CKEY[2 * tid + 1] = e1;
        __syncthreads();
        for (int j = k >> 1; j >= 128; j >>= 1) {
          int i = ((tid & ~(j - 1)) << 1) | (tid & (j - 1));
          u64 a = CKEY[i], bb = CKEY[i + j];
          bool desc = ((i & k) == 0);
          if (desc ? (a < bb) : (a > bb)) { CKEY[i] = bb; CKEY[i + j] = a; }
          __syncthreads();
        }
        e0 = CKEY[2 * tid]; e1 = CKEY[2 * tid + 1];
        REGCHAIN(k, 64);
      }
      CKEY[2 * tid] = e0; CKEY[2 * tid + 1] = e1;
      __syncthreads();
    }
    key = CKEY[tid];
    b = make_float4(0.f, 0.f, 0.f, 0.f);
    if (key != 0ull && tid < TOPK) {
      u32 idx = ~(u32)(key & 0xFFFFFFFFull);
      int iy = (int)idx / WID;
      int ix = (int)idx - iy * WID;
      float xx = (float)ix * 4.0f;
      float yy = (float)iy * 4.0f;
      const float* rb = reg + (size_t)n * 4 * HW;
      float r0 = rb[idx];
      float r1 = rb[HW + idx];
      float r2 = rb[2 * HW + idx];
      float r3 = rb[3 * HW + idx];
      b.y = yy - r0; b.z = xx + r1; b.w = yy + r2; b.x = xx - r3;
    }
  }
  float s = score_of(key);
  __syncthreads();   // all phase1 LDS reads complete before phase2 overlay writes

  // ---- validity + zero-fill (phase2 begins; SoA vbox/varea/mlds overlay phase1 arrays) ----
  bool vb = (tid < TOPK) && (s > THRESH) && (b.z - b.x >= 0.0f) && (b.w - b.y >= 0.0f);
  vx[tid] = 0.0f; vy[tid] = 0.0f; vz[tid] = 0.0f; vw[tid] = 0.0f;
  varea[tid] = 0.0f;
  u64 vm = __ballot(vb);
  if (lane == 0) wcnt[w] = (u32)__popcll(vm);
  if (tid < 16) { srem[tid] = 0ull; keepsh[tid] = 0ull; }
  __syncthreads();
  if (tid == 0) {
    u32 off = 0;
    for (int i = 0; i < 16; i++) { woff[i] = off; off += wcnt[i]; }
    int V = (int)off;
    int nch = (V + 63) >> 6;
    sV = V; snch = nch; snp = nch * (nch + 1) / 2;
  }
  __syncthreads();
  const int V = sV, nch = snch, npairs = snp;

  // ---- compact (rank order preserved); build pair->(c,k) tables ----
  int pos = -1;
  if (vb) {
    pos = (int)(woff[w] + (u32)__popcll(vm & ltmask));
    vx[pos] = b.x; vy[pos] = b.y; vz[pos] = b.z; vw[pos] = b.w;
    varea[pos] = area_of(b.x, b.y, b.z, b.w);
  }
  if (tid < npairs) {
    int p = tid, c = 0, base = 0;
    while (p >= base + (nch - c)) { base += nch - c; c++; }
    pc[tid] = c; pk[tid] = c + (p - base);
  }
  __syncthreads();

  // ---- matrix: row r of pair p -> bit j = iou(box_{64*k+i}, box_{64*c+j}) > T ----
  for (int r = w; r < npairs * 64; r += 16) {
    int p = r >> 6, i = r & 63;
    int c = pc[p], k = pk[p];
    int ri = k * 64 + i;                    // uniform across wave -> LDS broadcast (free)
    float rx0 = vx[ri], ry0 = vy[ri], rx1 = vz[ri], ry1 = vw[ri], ra = varea[ri];
    int ci = c * 64 + lane;                 // stride-4B -> conflict-free
    float cx0 = vx[ci], cy0 = vy[ci], cx1 = vz[ci], cy1 = vw[ci], ca = varea[ci];
    bool pred = iou_gt(rx0, ry0, rx1, ry1, ra, cx0, cy0, cx1, cy1, ca);
    u64 m = __ballot(pred);
    if (lane == 0) mlds[r] = m;
  }
  __syncthreads();

  // ---- greedy resolve (wave 0; pure bit-ops) ----
  if (tid < 64) {
    for (int c = 0; c < nch; c++) {
      int pbase = c * nch - (c * (c - 1)) / 2 - c;    // p(c,k) = pbase + k
      u64 diag = mlds[(pbase + c) * 64 + lane];
      u64 ainit = (V >= (c + 1) * 64) ? ~0ull
                : ((V > c * 64) ? ((1ull << (V - c * 64)) - 1ull) : 0ull);
      u64 alive;
      {
        u64 a = ainit & ~srem[c];
        u32 alo2 = __builtin_amdgcn_readfirstlane((u32)a);
        u32 ahi2 = __builtin_amdgcn_readfirstlane((u32)(a >> 32));
        alive = ((u64)ahi2 << 32) | alo2;
      }
      u32 rlo = (u32)diag, rhi = (u32)(diag >> 32);
      u64 cur = alive;
      while (cur) {
        int i = __ffsll(cur) - 1;
        u32 rl = __builtin_amdgcn_readlane(rlo, i);
        u32 rh = __builtin_amdgcn_readlane(rhi, i);
        u64 rowi = ((u64)rh << 32) | rl;
        u64 lowmask = (i == 63) ? ~0ull : ((1ull << (i + 1)) - 1ull);
        rowi &= ~lowmask;                            // suppress only later boxes
        alive &= ~rowi;
        cur &= ~rowi;
        cur &= cur - 1;
      }
      if (lane == 0) keepsh[c] = alive;
      const u64 K = alive;
      for (int k = c + 1; k < nch; k++) {
        bool sup = (mlds[(pbase + k) * 64 + lane] & K) != 0ull;
        u64 mres = __ballot(sup);
        if (lane == 0) srem[k] |= mres;
      }
    }
  }
  __syncthreads();

  // ---- output (each thread owns its rank; pos maps to compacted keep bit) ----
  u64 kb = (vb && pos >= 0) ? ((keepsh[pos >> 6] >> (pos & 63)) & 1ull) : 0ull;
  if (tid < TOPK) {
    float f = (float)kb;
    size_t ob = (size_t)n * (TOPK * 5) + (size_t)tid * 5;
    out[ob + 0] = kb ? b.x : 0.0f;
    out[ob + 1] = kb ? b.y : 0.0f;
    out[ob + 2] = kb ? b.z : 0.0f;
    out[ob + 3] = kb ? b.w : 0.0f;
    out[ob + 4] = kb ? s : 0.0f;
    out[(size_t)NIMG * TOPK * 5 + (size_t)n * TOPK + tid] = f;
  }
}

// ---------- single cooperative kernel: phase A -> grid sync -> phase B ----------
__global__ __launch_bounds__(1024) void mega_kernel(const float* __restrict__ cls,
                                                    const float* __restrict__ reg,
                                                    u32* __restrict__ pcnt,
                                                    u64* __restrict__ pcand,
                                                    float4* __restrict__ pbox,
                                                    float* __restrict__ out) {
  phaseA(cls, reg, pcnt, pcand, pbox, blockIdx.x);
  cg::this_grid().sync();
  if (blockIdx.x < NIMG) phaseB(cls, reg, pcnt, pcand, pbox, out, blockIdx.x);
}

// ---------- split kernels (fallback if cooperative launch unavailable) ----------
__global__ __launch_bounds__(1024) void phaseA_kernel(const float* __restrict__ cls,
                                                      const float* __restrict__ reg,
                                                      u32* __restrict__ pcnt,
                                                      u64* __restrict__ pcand,
                                                      float4* __restrict__ pbox) {
  phaseA(cls, reg, pcnt, pcand, pbox, blockIdx.x);
}

__global__ __launch_bounds__(1024) void phaseB_kernel(const float* __restrict__ cls,
                                                      const float* __restrict__ reg,
                                                      const u32* __restrict__ pcnt,
                                                      const u64* __restrict__ pcand,
                                                      const float4* __restrict__ pbox,
                                                      float* __restrict__ out) {
  phaseB(cls, reg, pcnt, pcand, pbox, out, blockIdx.x);
}

extern "C" void kernel_launch(void* const* d_in, const int* in_sizes, int n_in,
                              void* d_out, int out_size, void* d_ws, size_t ws_size,
                              hipStream_t stream) {
  const float* cls = (const float*)d_in[0];   // (32,1,384,384) f32
  const float* reg = (const float*)d_in[1];   // (32,4,384,384) f32
  float* out = (float*)d_out;                 // 160000 (out) + 32000 (keep) f32

  uint8_t* ws = (uint8_t*)d_ws;
  u32* pcnt = (u32*)(ws + PCNT_OFF);
  u64* pcand = (u64*)(ws + PCAND_OFF);
  float4* pbox = (float4*)(ws + PBOX_OFF);

  static int coop = -1;
  if (coop < 0) {
    int dev = 0, v = 0;
    hipGetDevice(&dev);
    hipDeviceGetAttribute(&v, hipDeviceAttributeCooperativeLaunch, dev);
    coop = v ? 1 : 0;
  }

  bool done = false;
  if (coop) {
    void* args[] = {(void*)&cls, (void*)&reg, (void*)&pcnt, (void*)&pcand, (void*)&pbox, (void*)&out};
    hipError_t e = hipLaunchCooperativeKernel((const void*)mega_kernel, dim3(SEGN), dim3(1024),
                                              args, 0, stream);
    done = (e == hipSuccess);
  }
  if (!done) {
    phaseA_kernel<<<dim3(SEGN), 1024, 0, stream>>>(cls, reg, pcnt, pcand, pbox);
    phaseB_kernel<<<dim3(NIMG), 1024, 0, stream>>>(cls, reg, pcnt, pcand, pbox, out);
  }
}

// Round 6
// 171.003 us; speedup vs baseline: 1.2229x; 1.2229x over previous
//
#include <hip/hip_runtime.h>
#include <stdint.h>

#define NIMG 32
#define WID 384
#define HW 147456            // 384*384
#define TOPK 1000
#define KPAD 1024
#define NBINS 512
#define BIN_SCALEF 512.0f
#define NSEG 6               // producer segments per image
#define SEGN (NIMG * NSEG)   // 192 producer blocks
#define SEGV4 6144           // float4 per segment (24576 floats = HW/6)
#define SEGCAP 384           // per-seg count ~246 +/- 15.6 (+8.9 sigma); overflow -> exact fallback
#define CANDCAP 2048
#define THRESH 0.05f
#define PREF_C 0.99f         // count(s>0.99) ~ 1475 +/- 38 per image; runtime-checked, exact fallback
#define NMS_T 0.4f
#define FINEBINS 256         // fine histogram bins over (0.99, 1.0] for rank placement
#define GRID (SEGN + NIMG)   // 224 blocks, 1 block/CU (96KB LDS) -> all resident
#define SPIN_MAX 100000u     // ~125ms worst case, then exact fallback (deadlock-free)

typedef unsigned long long u64;
typedef unsigned int u32;

// ---------------- workspace layout (bytes); total 1.77 MB == Round-4 proven footprint ----------------
#define DONE_OFF 0                                   // 32 u32 arrival counters (memset 0 each launch)
#define PCNT_OFF 1024                                // 192 u32
#define PCAND_OFF 4096                               // 192*384 u64 = 589824 -> ends 593920
#define PBOX_OFF 593920                              // 192*384 float4 = 1179648 -> ends 1773568

// ---------- numerics helpers (fp-contraction-proof, matches numpy f32) ----------
__device__ __forceinline__ float area_of(float x0, float y0, float x1, float y1) {
  float a = fmaxf(x1 - x0, 0.0f) * fmaxf(y1 - y0, 0.0f);
  asm volatile("" : "+v"(a));
  return a;
}

__device__ __forceinline__ bool iou_gt(float ax0, float ay0, float ax1, float ay1, float aa,
                                       float bx0, float by0, float bx1, float by1, float ba) {
  float ix1 = fmaxf(ax0, bx0);
  float iy1 = fmaxf(ay0, by0);
  float ix2 = fminf(ax1, bx1);
  float iy2 = fminf(ay1, by1);
  float iw = fmaxf(ix2 - ix1, 0.0f);
  float ih = fmaxf(iy2 - iy1, 0.0f);
  float inter = iw * ih;
  asm volatile("" : "+v"(inter));
  float uni = fmaxf(aa + ba - inter, 1e-9f);
  return (inter / uni) > NMS_T;
}

__device__ __forceinline__ u64 shflxor64(u64 v, int m) {
  int lo = __shfl_xor((int)(u32)v, m, 64);
  int hi = __shfl_xor((int)(u32)(v >> 32), m, 64);
  return ((u64)(u32)hi << 32) | (u32)lo;
}

__device__ __forceinline__ u64 make_key(float s, u32 idx) {
  u32 ord = __float_as_uint(s) | 0x80000000u;   // s > 0 always here
  return ((u64)ord << 32) | (u32)(~idx);        // desc score, ties asc index (lax.top_k)
}

__device__ __forceinline__ float score_of(u64 key) {
  return __uint_as_float((u32)(key >> 32) & 0x7FFFFFFFu);
}

__device__ __forceinline__ int bin_of(float s) {
  int b = (int)(s * BIN_SCALEF);
  return b < 0 ? 0 : (b > NBINS - 1 ? NBINS - 1 : b);
}

// fine bin over (0.99, 1.0]; monotone non-decreasing in s (f32 sub + mul + trunc are monotone)
__device__ __forceinline__ int finebin(u64 key) {
  float s = score_of(key);
  int b = (int)((s - 0.99f) * 25600.0f);
  return b < 0 ? 0 : (b > FINEBINS - 1 ? FINEBINS - 1 : b);
}

// reg-chain bitonic levels for stage k (jstart <= 64, via shuffles, no barriers) -- fallback only
#define REGCHAIN(K, JSTART) do {                                            \
    const bool desc_ = ((tid & ((K) >> 1)) == 0);                           \
    for (int j_ = (JSTART); j_ >= 2; j_ >>= 1) {                            \
      int h_ = j_ >> 1;                                                     \
      bool low_ = (tid & h_) == 0;                                          \
      u64 p0_ = shflxor64(e0, h_), p1_ = shflxor64(e1, h_);                 \
      bool tm_ = (low_ == desc_);                                           \
      e0 = tm_ ? (e0 > p0_ ? e0 : p0_) : (e0 < p0_ ? e0 : p0_);             \
      e1 = tm_ ? (e1 > p1_ ? e1 : p1_) : (e1 < p1_ ? e1 : p1_);             \
    }                                                                       \
    { u64 lo_ = e0 < e1 ? e0 : e1, hi_ = e0 < e1 ? e1 : e0;                 \
      e0 = desc_ ? hi_ : lo_; e1 = desc_ ? lo_ : hi_; }                     \
  } while (0)

// ---------- single kernel: 192 producer blocks + 32 consumer blocks, per-image release/acquire ----------
// Producer (image n, seg s): prefilter+decode -> stores drained at barrier -> tid0 threadfence
// (device-scope release) -> atomicAdd(done[n],1). Consumer n: bounded spin on done[n]==NSEG; on
// timeout runs the exact self-contained fallback (reads cls only) -> no deadlock, no co-residency
// correctness dependence. Grid 224 @ 96KB LDS = 1 block/CU -> all blocks resident in practice.
//
// Rank placement: fast-path scores all lie in (0.99, 1]; a 256-bin monotone histogram + prefix gives
// rank = C - binstart[b+1] + #{same-bin keys > k} (full u64 compare). Keys distinct (distinct idx),
// binning monotone in score, bins tile rank-space contiguously => exact total order == bitonic order.
// Exactness of valid-compact NMS: invalid boxes (w<0 / h<0 / s<=0.05 / rank>=1000) have keep=false
// from the start in the reference and can never suppress (clipped area/inter = 0 -> iou = 0 <= 0.4).
__global__ __launch_bounds__(1024) void mega_kernel(const float* __restrict__ cls,
                                                    const float* __restrict__ reg,
                                                    u32* __restrict__ done,
                                                    u32* __restrict__ pcnt,
                                                    u64* __restrict__ pcand,
                                                    float4* __restrict__ pbox,
                                                    float* __restrict__ out) {
  // ---- producer LDS ----
  __shared__ u64 lbuf[SEGCAP];
  __shared__ u32 lcnt;
  // ---- consumer LDS arena: phase1 (ranking) overlaid with phase2 (NMS) ----
  __shared__ __align__(16) unsigned char smem[90112];
  u64*    CKEY   = (u64*)smem;                    // [2048] keys; also fallback bitonic buffer (16KB)
  float4* CBOX   = (float4*)(smem + 16384);       // [2048] boxes (32KB) -> 49152
  u32*    BINNED = (u32*)(smem + 49152);          // [2048] bin-grouped candidate ids (8KB) -> 57344
  u64*    RKEY   = (u64*)(smem + 57344);          // [1024] rank-placed keys (8KB) -> 65536
  float4* RBOX   = (float4*)(smem + 65536);       // [1024] rank-placed boxes (16KB) -> 81920
  // phase2 overlay (all phase1 arrays dead before these are written; barriers enforce handoff)
  float* vx    = (float*)smem;                    // [1024] SoA boxes: conflict-free stride-4B reads
  float* vy    = (float*)(smem + 4096);
  float* vz    = (float*)(smem + 8192);
  float* vw    = (float*)(smem + 12288);
  float* varea = (float*)(smem + 16384);          // -> 20480
  u64*   mlds  = (u64*)(smem + 20480);            // [136*64] suppression triangle (68KB) -> 90112

  __shared__ u32 BINSTART[FINEBINS + 1];
  __shared__ u32 HIST[FINEBINS];       // histogram, then reused as per-bin fill counters
  __shared__ u32 scnt[NSEG];
  __shared__ u32 soff[NSEG];
  __shared__ u32 bs[NBINS];            // fallback only
  __shared__ u32 stmp[64];
  __shared__ int stbin;
  __shared__ u32 sflag, sfc;
  __shared__ int sC;
  __shared__ u32 wcnt[16], woff[16];
  __shared__ int pc[136], pk[136];
  __shared__ int sV, snch, snp;
  __shared__ u64 keepsh[16], srem[16];

  const int bid = blockIdx.x;
  const int tid = threadIdx.x;
  const int lane = tid & 63;
  const int w = tid >> 6;
  const u64 ltmask = (1ull << lane) - 1ull;

  if (bid < SEGN) {
    // ================= producer =================
    if (tid == 0) lcnt = 0;
    __syncthreads();
    const int n = bid / NSEG;
    const int sub = bid - n * NSEG;
    const float4* src = (const float4*)(cls + (size_t)n * HW) + sub * SEGV4;
    float4 A[6];
#pragma unroll
    for (int v = 0; v < 6; v++) A[v] = src[tid + v * 1024];   // 6 loads in flight

#pragma unroll
    for (int v = 0; v < 6; v++) {
      float ss[4] = {A[v].x, A[v].y, A[v].z, A[v].w};
#pragma unroll
      for (int c = 0; c < 4; c++) {
        float s = ss[c];
        bool pcd = s > PREF_C;
        u64 m = __ballot(pcd);
        if (m) {
          int ldr = __ffsll(m) - 1;
          u32 wb = 0;
          if (lane == ldr) wb = atomicAdd(&lcnt, (u32)__popcll(m));   // LDS atomic only
          wb = (u32)__shfl((int)wb, ldr, 64);
          if (pcd) {
            u32 pos = wb + (u32)__popcll(m & ltmask);
            if (pos < SEGCAP) lbuf[pos] = make_key(s, (u32)((sub * SEGV4 + tid + v * 1024) * 4 + c));
          }
        }
      }
    }
    __syncthreads();
    if (tid == 0) pcnt[bid] = (lcnt > SEGCAP) ? 0xFFFFFFFFu : lcnt;
    u32 c = lcnt < SEGCAP ? lcnt : (u32)SEGCAP;
    // decode boxes: idx local to this seg's 24K range (four 96KB reg spans); 192-block MLP
    const float* rb = reg + (size_t)n * 4 * HW;
    u64* pkk = pcand + (size_t)bid * SEGCAP;
    float4* pbb = pbox + (size_t)bid * SEGCAP;
    for (u32 i = tid; i < c; i += 1024) {
      u64 key = lbuf[i];
      u32 idx = ~(u32)(key & 0xFFFFFFFFull);
      int iy = (int)idx / WID;
      int ix = (int)idx - iy * WID;
      float xx = (float)ix * 4.0f;
      float yy = (float)iy * 4.0f;
      float r0 = rb[idx];
      float r1 = rb[HW + idx];
      float r2 = rb[2 * HW + idx];
      float r3 = rb[3 * HW + idx];
      float4 box;
      box.y = yy - r0; box.z = xx + r1; box.w = yy + r2; box.x = xx - r3;
      pkk[i] = key;
      pbb[i] = box;
    }
    __syncthreads();   // drains all global stores (vmcnt(0) before barrier)
    if (tid == 0) {
      __threadfence();                 // device-scope release
      atomicAdd(&done[n], 1u);         // arrival at coherent point
    }
    return;
  }

  // ================= consumer (one block per image) =================
  const int n = bid - SEGN;
  u32 timeout = 0;
  if (tid == 0) {
    timeout = 1;
    for (u32 it = 0; it < SPIN_MAX; ++it) {
      if (atomicAdd(&done[n], 0u) >= (u32)NSEG) { timeout = 0; break; }
      __builtin_amdgcn_s_sleep(32);
    }
  }
  __syncthreads();
  __threadfence();   // device-scope acquire (invalidate stale lines) before reading producer data

  // ---- init ----
  if (tid < NSEG) scnt[tid] = pcnt[n * NSEG + tid];
  RKEY[tid] = 0ull;
  if (tid < FINEBINS) HIST[tid] = 0;
  if (tid == 0) sfc = 0;
  __syncthreads();
  if (tid == 0) {
    u32 f = timeout;   // timeout -> ignore producer data entirely, run exact fallback
    u32 off = 0;
    for (int s = 0; s < NSEG; s++) {
      u32 cc = scnt[s];
      if (cc == 0xFFFFFFFFu) { f = 1; cc = 0; }
      soff[s] = off; off += cc;
    }
    if (off < TOPK || off > CANDCAP) f = 1;   // prefilter unusable -> exact fallback
    sflag = f; sC = (int)off;
  }
  __syncthreads();

  u64 key; float4 b;

  if (sflag == 0) {
    const int C = sC;
    // ---- coalesced gather over all slots (all 16 waves active; ~3 rounds) ----
    for (int slot = tid; slot < NSEG * SEGCAP; slot += 1024) {
      int s = slot / SEGCAP;
      int i = slot - s * SEGCAP;
      if ((u32)i < scnt[s]) {
        u32 o = soff[s] + (u32)i;
        CKEY[o] = pcand[(size_t)(n * NSEG + s) * SEGCAP + i];
        CBOX[o] = pbox[(size_t)(n * NSEG + s) * SEGCAP + i];
      }
    }
    __syncthreads();
    // ---- fine histogram ----
    for (int i = tid; i < C; i += 1024) atomicAdd(&HIST[finebin(CKEY[i])], 1u);
    __syncthreads();
    // ---- prefix (wave 0; 4 bins/lane) + zero HIST for reuse as fill counters ----
    if (tid < 64) {
      u32 h0 = HIST[lane * 4 + 0], h1 = HIST[lane * 4 + 1];
      u32 h2 = HIST[lane * 4 + 2], h3 = HIST[lane * 4 + 3];
      u32 t = h0 + h1 + h2 + h3;
      u32 incl = t;
#pragma unroll
      for (int d = 1; d < 64; d <<= 1) {
        u32 v = (u32)__shfl_up((int)incl, d, 64);
        if (lane >= d) incl += v;
      }
      u32 base = incl - t;
      BINSTART[lane * 4 + 0] = base;
      BINSTART[lane * 4 + 1] = base + h0;
      BINSTART[lane * 4 + 2] = base + h0 + h1;
      BINSTART[lane * 4 + 3] = base + h0 + h1 + h2;
      if (lane == 63) BINSTART[FINEBINS] = incl;    // == C
      HIST[lane * 4 + 0] = 0; HIST[lane * 4 + 1] = 0;
      HIST[lane * 4 + 2] = 0; HIST[lane * 4 + 3] = 0;
    }
    __syncthreads();
    // ---- scatter candidate ids into bin groups ----
    for (int i = tid; i < C; i += 1024) {
      int bb = finebin(CKEY[i]);
      u32 slot = atomicAdd(&HIST[bb], 1u);
      BINNED[BINSTART[bb] + slot] = (u32)i;
    }
    __syncthreads();
    // ---- exact rank + direct placement (top-1024 only; ~6 in-bin compares avg) ----
    for (int i = tid; i < C; i += 1024) {
      u64 k = CKEY[i];
      int bb = finebin(k);
      u32 s0 = BINSTART[bb], s1 = BINSTART[bb + 1];
      u32 g = 0;
      for (u32 j = s0; j < s1; j++) {
        u32 cj = BINNED[j];
        if (CKEY[cj] > k) g++;
      }
      u32 rank = (u32)C - s1 + g;
      if (rank < KPAD) { RKEY[rank] = k; RBOX[rank] = CBOX[i]; }
    }
    __syncthreads();
    key = RKEY[tid];
    b = (key != 0ull) ? RBOX[tid] : make_float4(0.f, 0.f, 0.f, 0.f);
  } else {
    // ---- exact fallback (self-contained: reads cls/reg only): histogram cutoff + bitonic + decode
    for (int i = tid; i < NBINS; i += 1024) bs[i] = 0;
    CKEY[tid] = 0ull; CKEY[tid + 1024] = 0ull;
    __syncthreads();
    const float* ci = cls + (size_t)n * HW;
    for (int base = 0; base < HW; base += 1024) {
      float s = ci[base + tid];
      if (s > THRESH) atomicAdd(&bs[bin_of(s)], 1u);
    }
    __syncthreads();
    if (tid < 64) {
      u32 cs = 0;
#pragma unroll
      for (int k2 = 0; k2 < 8; k2++) cs += bs[lane * 8 + k2];
      u32 s = cs;
#pragma unroll
      for (int d = 1; d < 64; d <<= 1) {
        u32 v = (u32)__shfl_down((int)s, d, 64);
        if (lane + d < 64) s += v;
      }
      stmp[lane] = s;
      u64 mask = __ballot(s >= TOPK);
      if (lane == 0) {
        int t = 0;
        if (mask) {
          int L = 63 - __clzll(mask);
          u32 acc = (L < 63) ? stmp[L + 1] : 0;
          for (int bb = L * 8 + 7; bb >= L * 8; bb--) {
            acc += bs[bb];
            if (acc >= TOPK) { t = bb; break; }
          }
        }
        stbin = t;
      }
    }
    __syncthreads();
    const int t = stbin;
    for (int base = 0; base < HW; base += 1024) {
      int i = base + tid;
      float s = ci[i];
      bool p = (s > THRESH) && (bin_of(s) >= t);
      u64 m = __ballot(p);
      if (m) {
        int ldr = __ffsll(m) - 1;
        u32 wb = 0;
        if (lane == ldr) wb = atomicAdd(&sfc, (u32)__popcll(m));
        wb = (u32)__shfl((int)wb, ldr, 64);
        if (p) { u32 pos = wb + (u32)__popcll(m & ltmask); if (pos < CANDCAP) CKEY[pos] = make_key(s, (u32)i); }
      }
    }
    __syncthreads();
    // hybrid bitonic sort (2048 keys, 2/thread; shfl for j<=64, LDS for j>=128)
    {
      u64 e0 = CKEY[2 * tid], e1 = CKEY[2 * tid + 1];
      REGCHAIN(2, 1); REGCHAIN(4, 2); REGCHAIN(8, 4); REGCHAIN(16, 8);
      REGCHAIN(32, 16); REGCHAIN(64, 32); REGCHAIN(128, 64);
      for (int k = 256; k <= CANDCAP; k <<= 1) {
        CKEY[2 * tid] = e0; CKEY[2 * tid + 1] = e1;
        __syncthreads();
        for (int j = k >> 1; j >= 128; j >>= 1) {
          int i = ((tid & ~(j - 1)) << 1) | (tid & (j - 1));
          u64 a = CKEY[i], bb = CKEY[i + j];
          bool desc = ((i & k) == 0);
          if (desc ? (a < bb) : (a > bb)) { CKEY[i] = bb; CKEY[i + j] = a; }
          __syncthreads();
        }
        e0 = CKEY[2 * tid]; e1 = CKEY[2 * tid + 1];
        REGCHAIN(k, 64);
      }
      CKEY[2 * tid] = e0; CKEY[2 * tid + 1] = e1;
      __syncthreads();
    }
    key = CKEY[tid];
    b = make_float4(0.f, 0.f, 0.f, 0.f);
    if (key != 0ull && tid < TOPK) {
      u32 idx = ~(u32)(key & 0xFFFFFFFFull);
      int iy = (int)idx / WID;
      int ix = (int)idx - iy * WID;
      float xx = (float)ix * 4.0f;
      float yy = (float)iy * 4.0f;
      const float* rb = reg + (size_t)n * 4 * HW;
      float r0 = rb[idx];
      float r1 = rb[HW + idx];
      float r2 = rb[2 * HW + idx];
      float r3 = rb[3 * HW + idx];
      b.y = yy - r0; b.z = xx + r1; b.w = yy + r2; b.x = xx - r3;
    }
  }
  float s = score_of(key);
  __syncthreads();   // all phase1 LDS reads complete before phase2 overlay writes

  // ---- validity + zero-fill (phase2 begins; SoA vbox/varea/mlds overlay phase1 arrays) ----
  bool vb = (tid < TOPK) && (s > THRESH) && (b.z - b.x >= 0.0f) && (b.w - b.y >= 0.0f);
  vx[tid] = 0.0f; vy[tid] = 0.0f; vz[tid] = 0.0f; vw[tid] = 0.0f;
  varea[tid] = 0.0f;
  u64 vm = __ballot(vb);
  if (lane == 0) wcnt[w] = (u32)__popcll(vm);
  if (tid < 16) { srem[tid] = 0ull; keepsh[tid] = 0ull; }
  __syncthreads();
  if (tid == 0) {
    u32 off = 0;
    for (int i = 0; i < 16; i++) { woff[i] = off; off += wcnt[i]; }
    int V = (int)off;
    int nch = (V + 63) >> 6;
    sV = V; snch = nch; snp = nch * (nch + 1) / 2;
  }
  __syncthreads();
  const int V = sV, nch = snch, npairs = snp;

  // ---- compact (rank order preserved); build pair->(c,k) tables ----
  int pos = -1;
  if (vb) {
    pos = (int)(woff[w] + (u32)__popcll(vm & ltmask));
    vx[pos] = b.x; vy[pos] = b.y; vz[pos] = b.z; vw[pos] = b.w;
    varea[pos] = area_of(b.x, b.y, b.z, b.w);
  }
  if (tid < npairs) {
    int p = tid, c = 0, base = 0;
    while (p >= base + (nch - c)) { base += nch - c; c++; }
    pc[tid] = c; pk[tid] = c + (p - base);
  }
  __syncthreads();

  // ---- matrix: row r of pair p -> bit j = iou(box_{64*k+i}, box_{64*c+j}) > T ----
  for (int r = w; r < npairs * 64; r += 16) {
    int p = r >> 6, i = r & 63;
    int c = pc[p], k = pk[p];
    int ri = k * 64 + i;                    // uniform across wave -> LDS broadcast (free)
    float rx0 = vx[ri], ry0 = vy[ri], rx1 = vz[ri], ry1 = vw[ri], ra = varea[ri];
    int ci = c * 64 + lane;                 // stride-4B -> conflict-free
    float cx0 = vx[ci], cy0 = vy[ci], cx1 = vz[ci], cy1 = vw[ci], ca = varea[ci];
    bool pred = iou_gt(rx0, ry0, rx1, ry1, ra, cx0, cy0, cx1, cy1, ca);
    u64 m = __ballot(pred);
    if (lane == 0) mlds[r] = m;
  }
  __syncthreads();

  // ---- greedy resolve (wave 0; pure bit-ops) ----
  if (tid < 64) {
    for (int c = 0; c < nch; c++) {
      int pbase = c * nch - (c * (c - 1)) / 2 - c;    // p(c,k) = pbase + k
      u64 diag = mlds[(pbase + c) * 64 + lane];
      u64 ainit = (V >= (c + 1) * 64) ? ~0ull
                : ((V > c * 64) ? ((1ull << (V - c * 64)) - 1ull) : 0ull);
      u64 alive;
      {
        u64 a = ainit & ~srem[c];
        u32 alo2 = __builtin_amdgcn_readfirstlane((u32)a);
        u32 ahi2 = __builtin_amdgcn_readfirstlane((u32)(a >> 32));
        alive = ((u64)ahi2 << 32) | alo2;
      }
      u32 rlo = (u32)diag, rhi = (u32)(diag >> 32);
      u64 cur = alive;
      while (cur) {
        int i = __ffsll(cur) - 1;
        u32 rl = __builtin_amdgcn_readlane(rlo, i);
        u32 rh = __builtin_amdgcn_readlane(rhi, i);
        u64 rowi = ((u64)rh << 32) | rl;
        u64 lowmask = (i == 63) ? ~0ull : ((1ull << (i + 1)) - 1ull);
        rowi &= ~lowmask;                            // suppress only later boxes
        alive &= ~rowi;
        cur &= ~rowi;
        cur &= cur - 1;
      }
      if (lane == 0) keepsh[c] = alive;
      const u64 K = alive;
      for (int k = c + 1; k < nch; k++) {
        bool sup = (mlds[(pbase + k) * 64 + lane] & K) != 0ull;
        u64 mres = __ballot(sup);
        if (lane == 0) srem[k] |= mres;
      }
    }
  }
  __syncthreads();

  // ---- output (each thread owns its rank; pos maps to compacted keep bit) ----
  u64 kb = (vb && pos >= 0) ? ((keepsh[pos >> 6] >> (pos & 63)) & 1ull) : 0ull;
  if (tid < TOPK) {
    float f = (float)kb;
    size_t ob = (size_t)n * (TOPK * 5) + (size_t)tid * 5;
    out[ob + 0] = kb ? b.x : 0.0f;
    out[ob + 1] = kb ? b.y : 0.0f;
    out[ob + 2] = kb ? b.z : 0.0f;
    out[ob + 3] = kb ? b.w : 0.0f;
    out[ob + 4] = kb ? s : 0.0f;
    out[(size_t)NIMG * TOPK * 5 + (size_t)n * TOPK + tid] = f;
  }
}

extern "C" void kernel_launch(void* const* d_in, const int* in_sizes, int n_in,
                              void* d_out, int out_size, void* d_ws, size_t ws_size,
                              hipStream_t stream) {
  const float* cls = (const float*)d_in[0];   // (32,1,384,384) f32
  const float* reg = (const float*)d_in[1];   // (32,4,384,384) f32
  float* out = (float*)d_out;                 // 160000 (out) + 32000 (keep) f32

  uint8_t* ws = (uint8_t*)d_ws;
  u32* done = (u32*)(ws + DONE_OFF);
  u32* pcnt = (u32*)(ws + PCNT_OFF);
  u64* pcand = (u64*)(ws + PCAND_OFF);
  float4* pbox = (float4*)(ws + PBOX_OFF);

  hipMemsetAsync(done, 0, NIMG * sizeof(u32), stream);   // arrival counters start at 0
  mega_kernel<<<dim3(GRID), 1024, 0, stream>>>(cls, reg, done, pcnt, pcand, pbox, out);
}

// Round 7
// 157.081 us; speedup vs baseline: 1.3313x; 1.0886x over previous
//
#include <hip/hip_runtime.h>
#include <stdint.h>

#define NIMG 32
#define WID 384
#define HW 147456            // 384*384
#define TOPK 1000
#define KPAD 1024
#define NBINS 512
#define BIN_SCALEF 512.0f
#define SEGCAP 128           // per-seg count ~82 +/- 9 (+5 sigma); overflow -> exact fallback
#define CANDCAP 2048
#define THRESH 0.05f
#define PREF_C 0.99f         // count(s>0.99) ~ 1475 +/- 38 per image; runtime-checked, exact fallback
#define NMS_T 0.4f
#define NBLK 18              // scan blocks per image (18*2048 float4 = 147456 floats)
#define FINEBINS 256         // fine histogram bins over (0.99, 1.0] for rank placement

typedef unsigned long long u64;
typedef unsigned int u32;

// ---------------- workspace layout (bytes); total 1.58 MB < 1.97 MB proven in Round 0 ----------------
#define PIMG_OFF 0                                   // 32 u32 per-image counters (memset 0 each launch)
#define PCAND_OFF 4096                               // 32*2048 u64 = 524288 -> ends 528384
#define PBOX_OFF 528384                              // 32*2048 float4 = 1048576 -> ends 1576960

// ---------- numerics helpers (fp-contraction-proof, matches numpy f32) ----------
__device__ __forceinline__ float area_of(float x0, float y0, float x1, float y1) {
  float a = fmaxf(x1 - x0, 0.0f) * fmaxf(y1 - y0, 0.0f);
  asm volatile("" : "+v"(a));
  return a;
}

__device__ __forceinline__ bool iou_gt(float ax0, float ay0, float ax1, float ay1, float aa,
                                       float bx0, float by0, float bx1, float by1, float ba) {
  float ix1 = fmaxf(ax0, bx0);
  float iy1 = fmaxf(ay0, by0);
  float ix2 = fminf(ax1, bx1);
  float iy2 = fminf(ay1, by1);
  float iw = fmaxf(ix2 - ix1, 0.0f);
  float ih = fmaxf(iy2 - iy1, 0.0f);
  float inter = iw * ih;
  asm volatile("" : "+v"(inter));
  float uni = fmaxf(aa + ba - inter, 1e-9f);
  return (inter / uni) > NMS_T;
}

__device__ __forceinline__ u64 shflxor64(u64 v, int m) {
  int lo = __shfl_xor((int)(u32)v, m, 64);
  int hi = __shfl_xor((int)(u32)(v >> 32), m, 64);
  return ((u64)(u32)hi << 32) | (u32)lo;
}

__device__ __forceinline__ u64 make_key(float s, u32 idx) {
  u32 ord = __float_as_uint(s) | 0x80000000u;   // s > 0 always here
  return ((u64)ord << 32) | (u32)(~idx);        // desc score, ties asc index (lax.top_k)
}

__device__ __forceinline__ float score_of(u64 key) {
  return __uint_as_float((u32)(key >> 32) & 0x7FFFFFFFu);
}

__device__ __forceinline__ int bin_of(float s) {
  int b = (int)(s * BIN_SCALEF);
  return b < 0 ? 0 : (b > NBINS - 1 ? NBINS - 1 : b);
}

// fine bin over (0.99, 1.0]; monotone non-decreasing in s (f32 sub + mul + trunc are monotone)
__device__ __forceinline__ int finebin(u64 key) {
  float s = score_of(key);
  int b = (int)((s - 0.99f) * 25600.0f);
  return b < 0 ? 0 : (b > FINEBINS - 1 ? FINEBINS - 1 : b);
}

// ---------- kernel 1: prefilter collect + decode + global compaction ----------
// Each block allocates a dense slice of its image's candidate array with ONE global atomicAdd.
// Arrival order across the 18 blocks is arbitrary -- rank placement in kernel 2 is order-agnostic.
// LDS overflow (lcnt>SEGCAP) poisons the counter (+0x100000) -> C>CANDCAP -> exact fallback.
__global__ __launch_bounds__(256) void scan_kernel(const float* __restrict__ cls,
                                                   const float* __restrict__ reg,
                                                   u32* __restrict__ pimgcnt,
                                                   u64* __restrict__ pcand,
                                                   float4* __restrict__ pbox) {
  __shared__ u64 lbuf[SEGCAP];
  __shared__ u32 lcnt, sbase;
  const int n = blockIdx.y;
  const int tid = threadIdx.x;
  const int lane = tid & 63;
  if (tid == 0) lcnt = 0;
  __syncthreads();

  const float4* src = (const float4*)(cls + (size_t)n * HW) + blockIdx.x * 2048;
  float4 A[8];
#pragma unroll
  for (int v = 0; v < 8; v++) A[v] = src[tid + v * 256];   // 8 loads in flight

  const u64 ltmask = (1ull << lane) - 1ull;
#pragma unroll
  for (int v = 0; v < 8; v++) {
    float ss[4] = {A[v].x, A[v].y, A[v].z, A[v].w};
#pragma unroll
    for (int c = 0; c < 4; c++) {
      float s = ss[c];
      bool pc = s > PREF_C;
      u64 m = __ballot(pc);
      if (m) {
        int ldr = __ffsll(m) - 1;
        u32 wb = 0;
        if (lane == ldr) wb = atomicAdd(&lcnt, (u32)__popcll(m));   // LDS atomic only
        wb = (u32)__shfl((int)wb, ldr, 64);
        if (pc) {
          u32 pos = wb + (u32)__popcll(m & ltmask);
          if (pos < SEGCAP) lbuf[pos] = make_key(s, (u32)((blockIdx.x * 2048 + tid + v * 256) * 4 + c));
        }
      }
    }
  }
  __syncthreads();
  const u32 total = lcnt;
  const u32 c = total < SEGCAP ? total : (u32)SEGCAP;
  if (tid == 0) {
    u32 add = (total > SEGCAP) ? (c + 0x100000u) : c;   // poison count on LDS overflow
    sbase = atomicAdd(&pimgcnt[n], add);
  }
  __syncthreads();
  const u32 base = sbase;
  // decode boxes here: idx local to this block's 8K range (four 32KB reg spans); 576-block MLP
  const float* rb = reg + (size_t)n * 4 * HW;
  u64* pk = pcand + (size_t)n * CANDCAP;
  float4* pb = pbox + (size_t)n * CANDCAP;
  for (u32 i = tid; i < c; i += 256) {
    u32 slot = base + i;
    if (slot < CANDCAP) {
      u64 key = lbuf[i];
      u32 idx = ~(u32)(key & 0xFFFFFFFFull);
      int iy = (int)idx / WID;
      int ix = (int)idx - iy * WID;
      float xx = (float)ix * 4.0f;
      float yy = (float)iy * 4.0f;
      float r0 = rb[idx];
      float r1 = rb[HW + idx];
      float r2 = rb[2 * HW + idx];
      float r3 = rb[3 * HW + idx];
      float4 box;
      box.y = yy - r0; box.z = xx + r1; box.w = yy + r2; box.x = xx - r3;
      pk[slot] = key;
      pb[slot] = box;
    }
  }
}

// reg-chain bitonic levels for stage k (jstart <= 64, via shuffles, no barriers) -- fallback only
#define REGCHAIN(K, JSTART) do {                                            \
    const bool desc_ = ((tid & ((K) >> 1)) == 0);                           \
    for (int j_ = (JSTART); j_ >= 2; j_ >>= 1) {                            \
      int h_ = j_ >> 1;                                                     \
      bool low_ = (tid & h_) == 0;                                          \
      u64 p0_ = shflxor64(e0, h_), p1_ = shflxor64(e1, h_);                 \
      bool tm_ = (low_ == desc_);                                           \
      e0 = tm_ ? (e0 > p0_ ? e0 : p0_) : (e0 < p0_ ? e0 : p0_);             \
      e1 = tm_ ? (e1 > p1_ ? e1 : p1_) : (e1 < p1_ ? e1 : p1_);             \
    }                                                                       \
    { u64 lo_ = e0 < e1 ? e0 : e1, hi_ = e0 < e1 ? e1 : e0;                 \
      e0 = desc_ ? hi_ : lo_; e1 = desc_ ? lo_ : hi_; }                     \
  } while (0)

// ---------- kernel 2 (fused): dense gather (early-issued) + rank-place + NMS + output ----------
// Rank placement: fast-path scores all lie in (0.99, 1]; a 256-bin monotone histogram + prefix gives
// rank = C - binstart[b+1] + #{same-bin keys > k} (full u64 compare). Keys distinct (distinct idx),
// binning monotone in score, bins tile rank-space contiguously => exact total order == top_k order,
// independent of the arbitrary arrival order from scan's atomic compaction.
// Exactness of valid-compact NMS: invalid boxes (w<0 / h<0 / s<=0.05 / rank>=1000) have keep=false
// from the start in the reference and can never suppress (clipped area/inter = 0 -> iou = 0 <= 0.4).
__global__ __launch_bounds__(1024) void fused_kernel(const float* __restrict__ cls,
                                                     const float* __restrict__ reg,
                                                     const u32* __restrict__ pimgcnt,
                                                     const u64* __restrict__ pcand,
                                                     const float4* __restrict__ pbox,
                                                     float* __restrict__ out) {
  // ---- manually-carved LDS arena: phase1 (ranking) overlaid with phase2 (NMS) ----
  __shared__ __align__(16) unsigned char smem[90112];
  u64*    CKEY   = (u64*)smem;                    // [2048] keys; also fallback bitonic buffer (16KB)
  float4* CBOX   = (float4*)(smem + 16384);       // [2048] boxes (32KB) -> 49152
  u32*    BINNED = (u32*)(smem + 49152);          // [2048] bin-grouped candidate ids (8KB) -> 57344
  u64*    RKEY   = (u64*)(smem + 57344);          // [1024] rank-placed keys (8KB) -> 65536
  float4* RBOX   = (float4*)(smem + 65536);       // [1024] rank-placed boxes (16KB) -> 81920
  // phase2 overlay (all phase1 arrays dead before these are written; barriers enforce handoff)
  float* vx    = (float*)smem;                    // [1024] SoA boxes: conflict-free stride-4B reads
  float* vy    = (float*)(smem + 4096);
  float* vz    = (float*)(smem + 8192);
  float* vw    = (float*)(smem + 12288);
  float* varea = (float*)(smem + 16384);          // -> 20480
  u64*   mlds  = (u64*)(smem + 20480);            // [136*64] suppression triangle (68KB) -> 90112

  __shared__ u32 BINSTART[FINEBINS + 1];
  __shared__ u32 HIST[FINEBINS];       // histogram, then reused as per-bin fill counters
  __shared__ u32 bs[NBINS];            // fallback only
  __shared__ u32 stmp[64];
  __shared__ int stbin;
  __shared__ u32 sflag, sfc;
  __shared__ int sC;
  __shared__ u32 wcnt[16], woff[16];
  __shared__ int pc[136], pk[136];
  __shared__ int sV, snch, snp;
  __shared__ u64 keepsh[16], srem[16];

  const int n = blockIdx.x;
  const int tid = threadIdx.x;
  const int lane = tid & 63;
  const int w = tid >> 6;
  const u64 ltmask = (1ull << lane) - 1ull;

  // ---- issue gather loads IMMEDIATELY (latency hides under init); use gated by i<C below ----
  // slots [0,C) are all written by scan's dense compaction; slots >=C are unused poison.
  const u64* gk = pcand + (size_t)n * CANDCAP;
  const float4* gb = pbox + (size_t)n * CANDCAP;
  u64 k0 = gk[tid];
  u64 k1 = gk[tid + 1024];
  float4 b0 = gb[tid];
  float4 b1 = gb[tid + 1024];

  // ---- init + flag (single barrier) ----
  RKEY[tid] = 0ull;
  if (tid < FINEBINS) HIST[tid] = 0;
  if (tid == 0) {
    u32 C = pimgcnt[n];
    sC = (int)C;
    sflag = (C < TOPK || C > CANDCAP) ? 1u : 0u;
    sfc = 0;
  }
  __syncthreads();                                          // B1

  u64 key; float4 b;

  if (sflag == 0) {
    const int C = sC;
    // ---- store to LDS + histogram from registers (one phase) ----
    if (tid < C)        { CKEY[tid] = k0;        CBOX[tid] = b0;        atomicAdd(&HIST[finebin(k0)], 1u); }
    if (tid + 1024 < C) { CKEY[tid + 1024] = k1; CBOX[tid + 1024] = b1; atomicAdd(&HIST[finebin(k1)], 1u); }
    __syncthreads();                                        // B2
    // ---- prefix (wave 0; 4 bins/lane) + zero HIST for reuse as fill counters ----
    if (tid < 64) {
      u32 h0 = HIST[lane * 4 + 0], h1 = HIST[lane * 4 + 1];
      u32 h2 = HIST[lane * 4 + 2], h3 = HIST[lane * 4 + 3];
      u32 t = h0 + h1 + h2 + h3;
      u32 incl = t;
#pragma unroll
      for (int d = 1; d < 64; d <<= 1) {
        u32 v = (u32)__shfl_up((int)incl, d, 64);
        if (lane >= d) incl += v;
      }
      u32 base = incl - t;
      BINSTART[lane * 4 + 0] = base;
      BINSTART[lane * 4 + 1] = base + h0;
      BINSTART[lane * 4 + 2] = base + h0 + h1;
      BINSTART[lane * 4 + 3] = base + h0 + h1 + h2;
      if (lane == 63) BINSTART[FINEBINS] = incl;    // == C
      HIST[lane * 4 + 0] = 0; HIST[lane * 4 + 1] = 0;
      HIST[lane * 4 + 2] = 0; HIST[lane * 4 + 3] = 0;
    }
    __syncthreads();                                        // B3
    // ---- scatter candidate ids into bin groups (keys from registers) ----
    if (tid < C) {
      int bb = finebin(k0);
      u32 slot = atomicAdd(&HIST[bb], 1u);
      BINNED[BINSTART[bb] + slot] = (u32)tid;
    }
    if (tid + 1024 < C) {
      int bb = finebin(k1);
      u32 slot = atomicAdd(&HIST[bb], 1u);
      BINNED[BINSTART[bb] + slot] = (u32)(tid + 1024);
    }
    __syncthreads();                                        // B4
    // ---- exact rank + direct placement (own key from register; ~6 in-bin compares avg) ----
    if (tid < C) {
      u64 k = k0;
      int bb = finebin(k);
      u32 s0 = BINSTART[bb], s1 = BINSTART[bb + 1];
      u32 g = 0;
      for (u32 j = s0; j < s1; j++) { if (CKEY[BINNED[j]] > k) g++; }
      u32 rank = (u32)C - s1 + g;
      if (rank < KPAD) { RKEY[rank] = k; RBOX[rank] = b0; }
    }
    if (tid + 1024 < C) {
      u64 k = k1;
      int bb = finebin(k);
      u32 s0 = BINSTART[bb], s1 = BINSTART[bb + 1];
      u32 g = 0;
      for (u32 j = s0; j < s1; j++) { if (CKEY[BINNED[j]] > k) g++; }
      u32 rank = (u32)C - s1 + g;
      if (rank < KPAD) { RKEY[rank] = k; RBOX[rank] = b1; }
    }
    __syncthreads();                                        // B5
    key = RKEY[tid];
    b = (key != 0ull) ? RBOX[tid] : make_float4(0.f, 0.f, 0.f, 0.f);
  } else {
    // ---- exact fallback (self-contained: reads cls/reg only): histogram cutoff + bitonic + decode
    for (int i = tid; i < NBINS; i += 1024) bs[i] = 0;
    CKEY[tid] = 0ull; CKEY[tid + 1024] = 0ull;
    __syncthreads();
    const float* ci = cls + (size_t)n * HW;
    for (int base = 0; base < HW; base += 1024) {
      float s = ci[base + tid];
      if (s > THRESH) atomicAdd(&bs[bin_of(s)], 1u);
    }
    __syncthreads();
    if (tid < 64) {
      u32 cs = 0;
#pragma unroll
      for (int k2 = 0; k2 < 8; k2++) cs += bs[lane * 8 + k2];
      u32 s = cs;
#pragma unroll
      for (int d = 1; d < 64; d <<= 1) {
        u32 v = (u32)__shfl_down((int)s, d, 64);
        if (lane + d < 64) s += v;
      }
      stmp[lane] = s;
      u64 mask = __ballot(s >= TOPK);
      if (lane == 0) {
        int t = 0;
        if (mask) {
          int L = 63 - __clzll(mask);
          u32 acc = (L < 63) ? stmp[L + 1] : 0;
          for (int bb = L * 8 + 7; bb >= L * 8; bb--) {
            acc += bs[bb];
            if (acc >= TOPK) { t = bb; break; }
          }
        }
        stbin = t;
      }
    }
    __syncthreads();
    const int t = stbin;
    for (int base = 0; base < HW; base += 1024) {
      int i = base + tid;
      float s = ci[i];
      bool p = (s > THRESH) && (bin_of(s) >= t);
      u64 m = __ballot(p);
      if (m) {
        int ldr = __ffsll(m) - 1;
        u32 wb = 0;
        if (lane == ldr) wb = atomicAdd(&sfc, (u32)__popcll(m));
        wb = (u32)__shfl((int)wb, ldr, 64);
        if (p) { u32 pos = wb + (u32)__popcll(m & ltmask); if (pos < CANDCAP) CKEY[pos] = make_key(s, (u32)i); }
      }
    }
    __syncthreads();
    // hybrid bitonic sort (2048 keys, 2/thread; shfl for j<=64, LDS for j>=128)
    {
      u64 e0 = CKEY[2 * tid], e1 = CKEY[2 * tid + 1];
      REGCHAIN(2, 1); REGCHAIN(4, 2); REGCHAIN(8, 4); REGCHAIN(16, 8);
      REGCHAIN(32, 16); REGCHAIN(64, 32); REGCHAIN(128, 64);
      for (int k = 256; k <= CANDCAP; k <<= 1) {
        CKEY[2 * tid] = e0; CKEY[2 * tid + 1] = e1;
        __syncthreads();
        for (int j = k >> 1; j >= 128; j >>= 1) {
          int i = ((tid & ~(j - 1)) << 1) | (tid & (j - 1));
          u64 a = CKEY[i], bb = CKEY[i + j];
          bool desc = ((i & k) == 0);
          if (desc ? (a < bb) : (a > bb)) { CKEY[i] = bb; CKEY[i + j] = a; }
          __syncthreads();
        }
        e0 = CKEY[2 * tid]; e1 = CKEY[2 * tid + 1];
        REGCHAIN(k, 64);
      }
      CKEY[2 * tid] = e0; CKEY[2 * tid + 1] = e1;
      __syncthreads();
    }
    key = CKEY[tid];
    b = make_float4(0.f, 0.f, 0.f, 0.f);
    if (key != 0ull && tid < TOPK) {
      u32 idx = ~(u32)(key & 0xFFFFFFFFull);
      int iy = (int)idx / WID;
      int ix = (int)idx - iy * WID;
      float xx = (float)ix * 4.0f;
      float yy = (float)iy * 4.0f;
      const float* rb = reg + (size_t)n * 4 * HW;
      float r0 = rb[idx];
      float r1 = rb[HW + idx];
      float r2 = rb[2 * HW + idx];
      float r3 = rb[3 * HW + idx];
      b.y = yy - r0; b.z = xx + r1; b.w = yy + r2; b.x = xx - r3;
    }
  }
  float s = score_of(key);
  __syncthreads();   // B6: all phase1 LDS reads complete before phase2 overlay writes

  // ---- validity + zero-fill (phase2 begins; SoA vbox/varea/mlds overlay phase1 arrays) ----
  bool vb = (tid < TOPK) && (s > THRESH) && (b.z - b.x >= 0.0f) && (b.w - b.y >= 0.0f);
  vx[tid] = 0.0f; vy[tid] = 0.0f; vz[tid] = 0.0f; vw[tid] = 0.0f;
  varea[tid] = 0.0f;
  u64 vm = __ballot(vb);
  if (lane == 0) wcnt[w] = (u32)__popcll(vm);
  if (tid < 16) { srem[tid] = 0ull; keepsh[tid] = 0ull; }
  __syncthreads();                                          // B7
  // ---- woff via wave-0 shfl prefix (replaces tid0 16-step serial chain) ----
  if (tid < 64) {
    u32 v = (lane < 16) ? wcnt[lane] : 0u;
    u32 incl = v;
#pragma unroll
    for (int d = 1; d < 16; d <<= 1) {
      u32 t = (u32)__shfl_up((int)incl, d, 64);
      if (lane >= d) incl += t;
    }
    if (lane < 16) woff[lane] = incl - v;
    if (lane == 15) {
      int V = (int)incl;
      int nch = (V + 63) >> 6;
      sV = V; snch = nch; snp = nch * (nch + 1) / 2;
    }
  }
  __syncthreads();                                          // B8
  const int V = sV, nch = snch, npairs = snp;

  // ---- compact (rank order preserved); build pair->(c,k) tables ----
  int pos = -1;
  if (vb) {
    pos = (int)(woff[w] + (u32)__popcll(vm & ltmask));
    vx[pos] = b.x; vy[pos] = b.y; vz[pos] = b.z; vw[pos] = b.w;
    varea[pos] = area_of(b.x, b.y, b.z, b.w);
  }
  if (tid < npairs) {
    int p = tid, c = 0, base = 0;
    while (p >= base + (nch - c)) { base += nch - c; c++; }
    pc[tid] = c; pk[tid] = c + (p - base);
  }
  __syncthreads();                                          // B9

  // ---- matrix: row r of pair p -> bit j = iou(box_{64*k+i}, box_{64*c+j}) > T ----
  // column-chunk (c) register cache: c changes only every ~4 iterations for a wave
  {
    int prevc = -1;
    float cx0 = 0.f, cy0 = 0.f, cx1 = 0.f, cy1 = 0.f, ca = 0.f;
    for (int r = w; r < npairs * 64; r += 16) {
      int p = r >> 6, i = r & 63;
      int c = pc[p], k = pk[p];
      if (c != prevc) {
        int ci = c * 64 + lane;               // stride-4B -> conflict-free
        cx0 = vx[ci]; cy0 = vy[ci]; cx1 = vz[ci]; cy1 = vw[ci]; ca = varea[ci];
        prevc = c;
      }
      int ri = k * 64 + i;                    // uniform across wave -> LDS broadcast (free)
      float rx0 = vx[ri], ry0 = vy[ri], rx1 = vz[ri], ry1 = vw[ri], ra = varea[ri];
      bool pred = iou_gt(rx0, ry0, rx1, ry1, ra, cx0, cy0, cx1, cy1, ca);
      u64 m = __ballot(pred);
      if (lane == 0) mlds[r] = m;
    }
  }
  __syncthreads();                                          // B10

  // ---- greedy resolve (wave 0; pure bit-ops) ----
  if (tid < 64) {
    for (int c = 0; c < nch; c++) {
      int pbase = c * nch - (c * (c - 1)) / 2 - c;    // p(c,k) = pbase + k
      u64 diag = mlds[(pbase + c) * 64 + lane];
      u64 ainit = (V >= (c + 1) * 64) ? ~0ull
                : ((V > c * 64) ? ((1ull << (V - c * 64)) - 1ull) : 0ull);
      u64 alive;
      {
        u64 a = ainit & ~srem[c];
        u32 alo2 = __builtin_amdgcn_readfirstlane((u32)a);
        u32 ahi2 = __builtin_amdgcn_readfirstlane((u32)(a >> 32));
        alive = ((u64)ahi2 << 32) | alo2;
      }
      u32 rlo = (u32)diag, rhi = (u32)(diag >> 32);
      u64 cur = alive;
      while (cur) {
        int i = __ffsll(cur) - 1;
        u32 rl = __builtin_amdgcn_readlane(rlo, i);
        u32 rh = __builtin_amdgcn_readlane(rhi, i);
        u64 rowi = ((u64)rh << 32) | rl;
        u64 lowmask = (i == 63) ? ~0ull : ((1ull << (i + 1)) - 1ull);
        rowi &= ~lowmask;                            // suppress only later boxes
        alive &= ~rowi;
        cur &= ~rowi;
        cur &= cur - 1;
      }
      if (lane == 0) keepsh[c] = alive;
      const u64 K = alive;
      for (int k = c + 1; k < nch; k++) {
        bool sup = (mlds[(pbase + k) * 64 + lane] & K) != 0ull;
        u64 mres = __ballot(sup);
        if (lane == 0) srem[k] |= mres;
      }
    }
  }
  __syncthreads();                                          // B11

  // ---- output (each thread owns its rank; pos maps to compacted keep bit) ----
  u64 kb = (vb && pos >= 0) ? ((keepsh[pos >> 6] >> (pos & 63)) & 1ull) : 0ull;
  if (tid < TOPK) {
    float f = (float)kb;
    size_t ob = (size_t)n * (TOPK * 5) + (size_t)tid * 5;
    out[ob + 0] = kb ? b.x : 0.0f;
    out[ob + 1] = kb ? b.y : 0.0f;
    out[ob + 2] = kb ? b.z : 0.0f;
    out[ob + 3] = kb ? b.w : 0.0f;
    out[ob + 4] = kb ? s : 0.0f;
    out[(size_t)NIMG * TOPK * 5 + (size_t)n * TOPK + tid] = f;
  }
}

extern "C" void kernel_launch(void* const* d_in, const int* in_sizes, int n_in,
                              void* d_out, int out_size, void* d_ws, size_t ws_size,
                              hipStream_t stream) {
  const float* cls = (const float*)d_in[0];   // (32,1,384,384) f32
  const float* reg = (const float*)d_in[1];   // (32,4,384,384) f32
  float* out = (float*)d_out;                 // 160000 (out) + 32000 (keep) f32

  uint8_t* ws = (uint8_t*)d_ws;
  u32* pimgcnt = (u32*)(ws + PIMG_OFF);
  u64* pcand = (u64*)(ws + PCAND_OFF);
  float4* pbox = (float4*)(ws + PBOX_OFF);

  hipMemsetAsync(pimgcnt, 0, NIMG * sizeof(u32), stream);   // per-image counters start at 0
  scan_kernel<<<dim3(NBLK, NIMG), 256, 0, stream>>>(cls, reg, pimgcnt, pcand, pbox);
  fused_kernel<<<NIMG, 1024, 0, stream>>>(cls, reg, pimgcnt, pcand, pbox, out);
}

// Round 8
// 153.505 us; speedup vs baseline: 1.3623x; 1.0233x over previous
//
#include <hip/hip_runtime.h>
#include <stdint.h>

#define NIMG 32
#define WID 384
#define HW 147456            // 384*384
#define TOPK 1000
#define KPAD 1024
#define NBINS 512
#define BIN_SCALEF 512.0f
#define SEGCAP 128           // per-seg count ~82 +/- 9 (+5 sigma); overflow -> exact fallback
#define NSLOT (NBLK * SEGCAP)  // 2304 fixed slots per image
#define CANDCAP 2048
#define THRESH 0.05f
#define PREF_C 0.99f         // count(s>0.99) ~ 1475 +/- 38 per image; runtime-checked, exact fallback
#define NMS_T 0.4f
#define NBLK 18              // scan blocks per image (18*2048 float4 = 147456 floats)
#define FINEBINS 256         // fine histogram bins over (0.99, 1.0] for rank placement

typedef unsigned long long u64;
typedef unsigned int u32;

// ---------------- workspace layout (bytes); total 1.77 MB == Round-4 proven footprint ----------------
#define PCNT_OFF 0                                   // 576 u32 (plain stores, no memset needed)
#define PCAND_OFF 4096                               // 576*128 u64 = 589824 -> ends 593920
#define PBOX_OFF  593920                             // 576*128 float4 = 1179648 -> ends 1773568

// ---------- numerics helpers (fp-contraction-proof, matches numpy f32) ----------
__device__ __forceinline__ float area_of(float x0, float y0, float x1, float y1) {
  float a = fmaxf(x1 - x0, 0.0f) * fmaxf(y1 - y0, 0.0f);
  asm volatile("" : "+v"(a));
  return a;
}

__device__ __forceinline__ bool iou_gt(float ax0, float ay0, float ax1, float ay1, float aa,
                                       float bx0, float by0, float bx1, float by1, float ba) {
  float ix1 = fmaxf(ax0, bx0);
  float iy1 = fmaxf(ay0, by0);
  float ix2 = fminf(ax1, bx1);
  float iy2 = fminf(ay1, by1);
  float iw = fmaxf(ix2 - ix1, 0.0f);
  float ih = fmaxf(iy2 - iy1, 0.0f);
  float inter = iw * ih;
  asm volatile("" : "+v"(inter));
  float uni = fmaxf(aa + ba - inter, 1e-9f);
  return (inter / uni) > NMS_T;
}

__device__ __forceinline__ u64 shflxor64(u64 v, int m) {
  int lo = __shfl_xor((int)(u32)v, m, 64);
  int hi = __shfl_xor((int)(u32)(v >> 32), m, 64);
  return ((u64)(u32)hi << 32) | (u32)lo;
}

__device__ __forceinline__ u64 make_key(float s, u32 idx) {
  u32 ord = __float_as_uint(s) | 0x80000000u;   // s > 0 always here
  return ((u64)ord << 32) | (u32)(~idx);        // desc score, ties asc index (lax.top_k)
}

__device__ __forceinline__ float score_of(u64 key) {
  return __uint_as_float((u32)(key >> 32) & 0x7FFFFFFFu);
}

__device__ __forceinline__ int bin_of(float s) {
  int b = (int)(s * BIN_SCALEF);
  return b < 0 ? 0 : (b > NBINS - 1 ? NBINS - 1 : b);
}

// fine bin over (0.99, 1.0]; monotone non-decreasing in s (f32 sub + mul + trunc are monotone)
__device__ __forceinline__ int finebin(u64 key) {
  float s = score_of(key);
  int b = (int)((s - 0.99f) * 25600.0f);
  return b < 0 ? 0 : (b > FINEBINS - 1 ? FINEBINS - 1 : b);
}

// ---------- kernel 1: prefilter collect + decode (verbatim Round-4 body, proven 154.9) ----------
__global__ __launch_bounds__(256) void scan_kernel(const float* __restrict__ cls,
                                                   const float* __restrict__ reg,
                                                   u32* __restrict__ pcnt,
                                                   u64* __restrict__ pcand,
                                                   float4* __restrict__ pbox) {
  __shared__ u64 lbuf[SEGCAP];
  __shared__ u32 lcnt;
  const int n = blockIdx.y;
  const int tid = threadIdx.x;
  const int lane = tid & 63;
  if (tid == 0) lcnt = 0;
  __syncthreads();

  const float4* src = (const float4*)(cls + (size_t)n * HW) + blockIdx.x * 2048;
  float4 A[8];
#pragma unroll
  for (int v = 0; v < 8; v++) A[v] = src[tid + v * 256];   // 8 loads in flight

  const u64 ltmask = (1ull << lane) - 1ull;
#pragma unroll
  for (int v = 0; v < 8; v++) {
    float ss[4] = {A[v].x, A[v].y, A[v].z, A[v].w};
#pragma unroll
    for (int c = 0; c < 4; c++) {
      float s = ss[c];
      bool pc = s > PREF_C;
      u64 m = __ballot(pc);
      if (m) {
        int ldr = __ffsll(m) - 1;
        u32 wb = 0;
        if (lane == ldr) wb = atomicAdd(&lcnt, (u32)__popcll(m));   // LDS atomic only
        wb = (u32)__shfl((int)wb, ldr, 64);
        if (pc) {
          u32 pos = wb + (u32)__popcll(m & ltmask);
          if (pos < SEGCAP) lbuf[pos] = make_key(s, (u32)((blockIdx.x * 2048 + tid + v * 256) * 4 + c));
        }
      }
    }
  }
  __syncthreads();
  const int seg = n * NBLK + blockIdx.x;
  if (tid == 0) pcnt[seg] = (lcnt > SEGCAP) ? 0xFFFFFFFFu : lcnt;
  u32 c = lcnt < SEGCAP ? lcnt : (u32)SEGCAP;
  // decode boxes here: idx local to this block's 8K range (four 32KB reg spans); 576-block MLP
  const float* rb = reg + (size_t)n * 4 * HW;
  u64* pk = pcand + (size_t)seg * SEGCAP;
  float4* pb = pbox + (size_t)seg * SEGCAP;
  for (u32 i = tid; i < c; i += 256) {
    u64 key = lbuf[i];
    u32 idx = ~(u32)(key & 0xFFFFFFFFull);
    int iy = (int)idx / WID;
    int ix = (int)idx - iy * WID;
    float xx = (float)ix * 4.0f;
    float yy = (float)iy * 4.0f;
    float r0 = rb[idx];
    float r1 = rb[HW + idx];
    float r2 = rb[2 * HW + idx];
    float r3 = rb[3 * HW + idx];
    float4 box;
    box.y = yy - r0; box.z = xx + r1; box.w = yy + r2; box.x = xx - r3;
    pk[i] = key;
    pb[i] = box;
  }
}

// reg-chain bitonic levels for stage k (jstart <= 64, via shuffles, no barriers) -- fallback only
#define REGCHAIN(K, JSTART) do {                                            \
    const bool desc_ = ((tid & ((K) >> 1)) == 0);                           \
    for (int j_ = (JSTART); j_ >= 2; j_ >>= 1) {                            \
      int h_ = j_ >> 1;                                                     \
      bool low_ = (tid & h_) == 0;                                          \
      u64 p0_ = shflxor64(e0, h_), p1_ = shflxor64(e1, h_);                 \
      bool tm_ = (low_ == desc_);                                           \
      e0 = tm_ ? (e0 > p0_ ? e0 : p0_) : (e0 < p0_ ? e0 : p0_);             \
      e1 = tm_ ? (e1 > p1_ ? e1 : p1_) : (e1 < p1_ ? e1 : p1_);             \
    }                                                                       \
    { u64 lo_ = e0 < e1 ? e0 : e1, hi_ = e0 < e1 ? e1 : e0;                 \
      e0 = desc_ ? hi_ : lo_; e1 = desc_ ? lo_ : hi_; }                     \
  } while (0)

// ---------- kernel 2 (fused): early-issued segment gather + rank-place + NMS + output ----------
// Early issue: candidate slots live at FIXED addresses (seg*SEGCAP+i), so all loads are issued
// before the first barrier; unwritten slots (i >= scnt[seg]) hold workspace poison and are gated
// out after the counts arrive (wave-0 shfl prefix, also pre-barrier). No memset, no global atomic.
// Rank placement: fast-path scores all lie in (0.99, 1]; a 256-bin monotone histogram + prefix gives
// rank = C - binstart[b+1] + #{same-bin keys > k} (full u64 compare). Keys distinct (distinct idx),
// binning monotone in score, bins tile rank-space contiguously => exact total order == top_k order.
// Exactness of valid-compact NMS: invalid boxes (w<0 / h<0 / s<=0.05 / rank>=1000) have keep=false
// from the start in the reference and can never suppress (clipped area/inter = 0 -> iou = 0 <= 0.4).
__global__ __launch_bounds__(1024) void fused_kernel(const float* __restrict__ cls,
                                                     const float* __restrict__ reg,
                                                     const u32* __restrict__ pcnt,
                                                     const u64* __restrict__ pcand,
                                                     const float4* __restrict__ pbox,
                                                     float* __restrict__ out) {
  // ---- manually-carved LDS arena: phase1 (ranking) overlaid with phase2 (NMS) ----
  __shared__ __align__(16) unsigned char smem[90112];
  u64*    CKEY   = (u64*)smem;                    // [2048] dense keys; also fallback bitonic buffer (16KB)
  u32*    BINNED = (u32*)(smem + 16384);          // [2048] bin-grouped candidate ids (8KB) -> 24576
  u64*    RKEY   = (u64*)(smem + 24576);          // [1024] rank-placed keys (8KB) -> 32768
  float4* RBOX   = (float4*)(smem + 32768);       // [1024] rank-placed boxes (16KB) -> 49152
  // phase2 overlay (all phase1 arrays dead before these are written; barriers enforce handoff)
  float* vx    = (float*)smem;                    // [1024] SoA boxes: conflict-free stride-4B reads
  float* vy    = (float*)(smem + 4096);
  float* vz    = (float*)(smem + 8192);
  float* vw    = (float*)(smem + 12288);
  float* varea = (float*)(smem + 16384);          // -> 20480
  u64*   mlds  = (u64*)(smem + 20480);            // [136*64] suppression triangle (68KB) -> 90112

  __shared__ u32 BINSTART[FINEBINS + 1];
  __shared__ u32 HIST[FINEBINS];       // histogram, then reused as per-bin fill counters
  __shared__ u32 scnt[NBLK];
  __shared__ u32 soff[NBLK];
  __shared__ u32 bs[NBINS];            // fallback only
  __shared__ u32 stmp[64];
  __shared__ int stbin;
  __shared__ u32 sflag, sfc;
  __shared__ int sC;
  __shared__ u32 wcnt[16], woff[16];
  __shared__ int pc[136], pk[136];
  __shared__ int sV, snch, snp;
  __shared__ u64 keepsh[16], srem[16];

  const int n = blockIdx.x;
  const int tid = threadIdx.x;
  const int lane = tid & 63;
  const int w = tid >> 6;
  const u64 ltmask = (1ull << lane) - 1ull;

  // ---- issue ALL candidate-slot loads IMMEDIATELY (fixed segment-layout addresses) ----
  const u64* gk = pcand + (size_t)n * NSLOT;
  const float4* gb = pbox + (size_t)n * NSLOT;
  u64 k0 = gk[tid];
  u64 k1 = gk[tid + 1024];
  float4 b0 = gb[tid];
  float4 b1 = gb[tid + 1024];
  u64 k2 = 0; float4 b2 = make_float4(0.f, 0.f, 0.f, 0.f);
  if (tid < NSLOT - 2048) { k2 = gk[tid + 2048]; b2 = gb[tid + 2048]; }

  // ---- wave 0: counts + shfl prefix + flag (concurrent with the loads above) ----
  if (tid < 64) {
    u32 cnt = 0; bool ovf = false;
    if (lane < NBLK) {
      cnt = pcnt[n * NBLK + lane];
      if (cnt == 0xFFFFFFFFu) { ovf = true; cnt = 0; }
    }
    u32 incl = cnt;
#pragma unroll
    for (int d = 1; d < 32; d <<= 1) {
      u32 v = (u32)__shfl_up((int)incl, d, 64);
      if (lane >= d) incl += v;
    }
    if (lane < NBLK) { scnt[lane] = cnt; soff[lane] = incl - cnt; }
    u64 om = __ballot(ovf);
    if (lane == NBLK - 1) {
      u32 C = incl;
      sC = (int)C;
      sflag = (om != 0ull || C < TOPK || C > CANDCAP) ? 1u : 0u;
      sfc = 0;
    }
  }
  RKEY[tid] = 0ull;
  if (tid < FINEBINS) HIST[tid] = 0;
  __syncthreads();                                          // B1

  u64 key; float4 b;

  if (sflag == 0) {
    const int C = sC;
    // ---- per-slot validity + dense CKEY store + histogram from registers (one phase) ----
    u32 o0 = 0, o1 = 0, o2 = 0; bool v0 = false, v1 = false, v2 = false;
    {
      int seg = tid >> 7, i = tid & 127;
      if ((u32)i < scnt[seg]) { v0 = true; o0 = soff[seg] + (u32)i; CKEY[o0] = k0; atomicAdd(&HIST[finebin(k0)], 1u); }
    }
    {
      int slot = tid + 1024; int seg = slot >> 7, i = slot & 127;
      if ((u32)i < scnt[seg]) { v1 = true; o1 = soff[seg] + (u32)i; CKEY[o1] = k1; atomicAdd(&HIST[finebin(k1)], 1u); }
    }
    if (tid < NSLOT - 2048) {
      int slot = tid + 2048; int seg = slot >> 7, i = slot & 127;
      if ((u32)i < scnt[seg]) { v2 = true; o2 = soff[seg] + (u32)i; CKEY[o2] = k2; atomicAdd(&HIST[finebin(k2)], 1u); }
    }
    __syncthreads();                                        // B2
    // ---- prefix (wave 0; 4 bins/lane) + zero HIST for reuse as fill counters ----
    if (tid < 64) {
      u32 h0 = HIST[lane * 4 + 0], h1 = HIST[lane * 4 + 1];
      u32 h2 = HIST[lane * 4 + 2], h3 = HIST[lane * 4 + 3];
      u32 t = h0 + h1 + h2 + h3;
      u32 incl = t;
#pragma unroll
      for (int d = 1; d < 64; d <<= 1) {
        u32 v = (u32)__shfl_up((int)incl, d, 64);
        if (lane >= d) incl += v;
      }
      u32 base = incl - t;
      BINSTART[lane * 4 + 0] = base;
      BINSTART[lane * 4 + 1] = base + h0;
      BINSTART[lane * 4 + 2] = base + h0 + h1;
      BINSTART[lane * 4 + 3] = base + h0 + h1 + h2;
      if (lane == 63) BINSTART[FINEBINS] = incl;    // == C
      HIST[lane * 4 + 0] = 0; HIST[lane * 4 + 1] = 0;
      HIST[lane * 4 + 2] = 0; HIST[lane * 4 + 3] = 0;
    }
    __syncthreads();                                        // B3
    // ---- scatter candidate ids into bin groups (keys from registers) ----
    if (v0) { int bb = finebin(k0); u32 sl = atomicAdd(&HIST[bb], 1u); BINNED[BINSTART[bb] + sl] = o0; }
    if (v1) { int bb = finebin(k1); u32 sl = atomicAdd(&HIST[bb], 1u); BINNED[BINSTART[bb] + sl] = o1; }
    if (v2) { int bb = finebin(k2); u32 sl = atomicAdd(&HIST[bb], 1u); BINNED[BINSTART[bb] + sl] = o2; }
    __syncthreads();                                        // B4
    // ---- exact rank + direct placement (own key from register; ~6 in-bin compares avg) ----
    if (v0) {
      int bb = finebin(k0);
      u32 s0 = BINSTART[bb], s1 = BINSTART[bb + 1], g = 0;
      for (u32 j = s0; j < s1; j++) { if (CKEY[BINNED[j]] > k0) g++; }
      u32 rank = (u32)C - s1 + g;
      if (rank < KPAD) { RKEY[rank] = k0; RBOX[rank] = b0; }
    }
    if (v1) {
      int bb = finebin(k1);
      u32 s0 = BINSTART[bb], s1 = BINSTART[bb + 1], g = 0;
      for (u32 j = s0; j < s1; j++) { if (CKEY[BINNED[j]] > k1) g++; }
      u32 rank = (u32)C - s1 + g;
      if (rank < KPAD) { RKEY[rank] = k1; RBOX[rank] = b1; }
    }
    if (v2) {
      int bb = finebin(k2);
      u32 s0 = BINSTART[bb], s1 = BINSTART[bb + 1], g = 0;
      for (u32 j = s0; j < s1; j++) { if (CKEY[BINNED[j]] > k2) g++; }
      u32 rank = (u32)C - s1 + g;
      if (rank < KPAD) { RKEY[rank] = k2; RBOX[rank] = b2; }
    }
    __syncthreads();                                        // B5
    key = RKEY[tid];
    b = (key != 0ull) ? RBOX[tid] : make_float4(0.f, 0.f, 0.f, 0.f);
  } else {
    // ---- exact fallback (self-contained: reads cls/reg only): histogram cutoff + bitonic + decode
    for (int i = tid; i < NBINS; i += 1024) bs[i] = 0;
    CKEY[tid] = 0ull; CKEY[tid + 1024] = 0ull;
    __syncthreads();
    const float* ci = cls + (size_t)n * HW;
    for (int base = 0; base < HW; base += 1024) {
      float s = ci[base + tid];
      if (s > THRESH) atomicAdd(&bs[bin_of(s)], 1u);
    }
    __syncthreads();
    if (tid < 64) {
      u32 cs = 0;
#pragma unroll
      for (int k2i = 0; k2i < 8; k2i++) cs += bs[lane * 8 + k2i];
      u32 s = cs;
#pragma unroll
      for (int d = 1; d < 64; d <<= 1) {
        u32 v = (u32)__shfl_down((int)s, d, 64);
        if (lane + d < 64) s += v;
      }
      stmp[lane] = s;
      u64 mask = __ballot(s >= TOPK);
      if (lane == 0) {
        int t = 0;
        if (mask) {
          int L = 63 - __clzll(mask);
          u32 acc = (L < 63) ? stmp[L + 1] : 0;
          for (int bb = L * 8 + 7; bb >= L * 8; bb--) {
            acc += bs[bb];
            if (acc >= TOPK) { t = bb; break; }
          }
        }
        stbin = t;
      }
    }
    __syncthreads();
    const int t = stbin;
    for (int base = 0; base < HW; base += 1024) {
      int i = base + tid;
      float s = ci[i];
      bool p = (s > THRESH) && (bin_of(s) >= t);
      u64 m = __ballot(p);
      if (m) {
        int ldr = __ffsll(m) - 1;
        u32 wb = 0;
        if (lane == ldr) wb = atomicAdd(&sfc, (u32)__popcll(m));
        wb = (u32)__shfl((int)wb, ldr, 64);
        if (p) { u32 pos = wb + (u32)__popcll(m & ltmask); if (pos < CANDCAP) CKEY[pos] = make_key(s, (u32)i); }
      }
    }
    __syncthreads();
    // hybrid bitonic sort (2048 keys, 2/thread; shfl for j<=64, LDS for j>=128)
    {
      u64 e0 = CKEY[2 * tid], e1 = CKEY[2 * tid + 1];
      REGCHAIN(2, 1); REGCHAIN(4, 2); REGCHAIN(8, 4); REGCHAIN(16, 8);
      REGCHAIN(32, 16); REGCHAIN(64, 32); REGCHAIN(128, 64);
      for (int k = 256; k <= CANDCAP; k <<= 1) {
        CKEY[2 * tid] = e0; CKEY[2 * tid + 1] = e1;
        __syncthreads();
        for (int j = k >> 1; j >= 128; j >>= 1) {
          int i = ((tid & ~(j - 1)) << 1) | (tid & (j - 1));
          u64 a = CKEY[i], bb = CKEY[i + j];
          bool desc = ((i & k) == 0);
          if (desc ? (a < bb) : (a > bb)) { CKEY[i] = bb; CKEY[i + j] = a; }
          __syncthreads();
        }
        e0 = CKEY[2 * tid]; e1 = CKEY[2 * tid + 1];
        REGCHAIN(k, 64);
      }
      CKEY[2 * tid] = e0; CKEY[2 * tid + 1] = e1;
      __syncthreads();
    }
    key = CKEY[tid];
    b = make_float4(0.f, 0.f, 0.f, 0.f);
    if (key != 0ull && tid < TOPK) {
      u32 idx = ~(u32)(key & 0xFFFFFFFFull);
      int iy = (int)idx / WID;
      int ix = (int)idx - iy * WID;
      float xx = (float)ix * 4.0f;
      float yy = (float)iy * 4.0f;
      const float* rb = reg + (size_t)n * 4 * HW;
      float r0 = rb[idx];
      float r1 = rb[HW + idx];
      float r2 = rb[2 * HW + idx];
      float r3 = rb[3 * HW + idx];
      b.y = yy - r0; b.z = xx + r1; b.w = yy + r2; b.x = xx - r3;
    }
  }
  float s = score_of(key);
  __syncthreads();   // B6: all phase1 LDS reads complete before phase2 overlay writes

  // ---- validity + zero-fill (phase2 begins; SoA vbox/varea/mlds overlay phase1 arrays) ----
  bool vb = (tid < TOPK) && (s > THRESH) && (b.z - b.x >= 0.0f) && (b.w - b.y >= 0.0f);
  vx[tid] = 0.0f; vy[tid] = 0.0f; vz[tid] = 0.0f; vw[tid] = 0.0f;
  varea[tid] = 0.0f;
  u64 vm = __ballot(vb);
  if (lane == 0) wcnt[w] = (u32)__popcll(vm);
  if (tid < 16) { srem[tid] = 0ull; keepsh[tid] = 0ull; }
  __syncthreads();                                          // B7
  // ---- woff via wave-0 shfl prefix ----
  if (tid < 64) {
    u32 v = (lane < 16) ? wcnt[lane] : 0u;
    u32 incl = v;
#pragma unroll
    for (int d = 1; d < 16; d <<= 1) {
      u32 t = (u32)__shfl_up((int)incl, d, 64);
      if (lane >= d) incl += t;
    }
    if (lane < 16) woff[lane] = incl - v;
    if (lane == 15) {
      int V = (int)incl;
      int nch = (V + 63) >> 6;
      sV = V; snch = nch; snp = nch * (nch + 1) / 2;
    }
  }
  __syncthreads();                                          // B8
  const int V = sV, nch = snch, npairs = snp;

  // ---- compact (rank order preserved); build pair->(c,k) tables ----
  int pos = -1;
  if (vb) {
    pos = (int)(woff[w] + (u32)__popcll(vm & ltmask));
    vx[pos] = b.x; vy[pos] = b.y; vz[pos] = b.z; vw[pos] = b.w;
    varea[pos] = area_of(b.x, b.y, b.z, b.w);
  }
  if (tid < npairs) {
    int p = tid, c = 0, base = 0;
    while (p >= base + (nch - c)) { base += nch - c; c++; }
    pc[tid] = c; pk[tid] = c + (p - base);
  }
  __syncthreads();                                          // B9

  // ---- matrix: row r of pair p -> bit j = iou(box_{64*k+i}, box_{64*c+j}) > T ----
  // column-chunk (c) register cache: c changes only every ~4 iterations for a wave
  {
    int prevc = -1;
    float cx0 = 0.f, cy0 = 0.f, cx1 = 0.f, cy1 = 0.f, ca = 0.f;
    for (int r = w; r < npairs * 64; r += 16) {
      int p = r >> 6, i = r & 63;
      int c = pc[p], k = pk[p];
      if (c != prevc) {
        int ci = c * 64 + lane;               // stride-4B -> conflict-free
        cx0 = vx[ci]; cy0 = vy[ci]; cx1 = vz[ci]; cy1 = vw[ci]; ca = varea[ci];
        prevc = c;
      }
      int ri = k * 64 + i;                    // uniform across wave -> LDS broadcast (free)
      float rx0 = vx[ri], ry0 = vy[ri], rx1 = vz[ri], ry1 = vw[ri], ra = varea[ri];
      bool pred = iou_gt(rx0, ry0, rx1, ry1, ra, cx0, cy0, cx1, cy1, ca);
      u64 m = __ballot(pred);
      if (lane == 0) mlds[r] = m;
    }
  }
  __syncthreads();                                          // B10

  // ---- greedy resolve (wave 0; pure bit-ops) ----
  if (tid < 64) {
    for (int c = 0; c < nch; c++) {
      int pbase = c * nch - (c * (c - 1)) / 2 - c;    // p(c,k) = pbase + k
      u64 diag = mlds[(pbase + c) * 64 + lane];
      u64 ainit = (V >= (c + 1) * 64) ? ~0ull
                : ((V > c * 64) ? ((1ull << (V - c * 64)) - 1ull) : 0ull);
      u64 alive;
      {
        u64 a = ainit & ~srem[c];
        u32 alo2 = __builtin_amdgcn_readfirstlane((u32)a);
        u32 ahi2 = __builtin_amdgcn_readfirstlane((u32)(a >> 32));
        alive = ((u64)ahi2 << 32) | alo2;
      }
      u32 rlo = (u32)diag, rhi = (u32)(diag >> 32);
      u64 cur = alive;
      while (cur) {
        int i = __ffsll(cur) - 1;
        u32 rl = __builtin_amdgcn_readlane(rlo, i);
        u32 rh = __builtin_amdgcn_readlane(rhi, i);
        u64 rowi = ((u64)rh << 32) | rl;
        u64 lowmask = (i == 63) ? ~0ull : ((1ull << (i + 1)) - 1ull);
        rowi &= ~lowmask;                            // suppress only later boxes
        alive &= ~rowi;
        cur &= ~rowi;
        cur &= cur - 1;
      }
      if (lane == 0) keepsh[c] = alive;
      const u64 K = alive;
      for (int k = c + 1; k < nch; k++) {
        bool sup = (mlds[(pbase + k) * 64 + lane] & K) != 0ull;
        u64 mres = __ballot(sup);
        if (lane == 0) srem[k] |= mres;
      }
    }
  }
  __syncthreads();                                          // B11

  // ---- output (each thread owns its rank; pos maps to compacted keep bit) ----
  u64 kb = (vb && pos >= 0) ? ((keepsh[pos >> 6] >> (pos & 63)) & 1ull) : 0ull;
  if (tid < TOPK) {
    float f = (float)kb;
    size_t ob = (size_t)n * (TOPK * 5) + (size_t)tid * 5;
    out[ob + 0] = kb ? b.x : 0.0f;
    out[ob + 1] = kb ? b.y : 0.0f;
    out[ob + 2] = kb ? b.z : 0.0f;
    out[ob + 3] = kb ? b.w : 0.0f;
    out[ob + 4] = kb ? s : 0.0f;
    out[(size_t)NIMG * TOPK * 5 + (size_t)n * TOPK + tid] = f;
  }
}

extern "C" void kernel_launch(void* const* d_in, const int* in_sizes, int n_in,
                              void* d_out, int out_size, void* d_ws, size_t ws_size,
                              hipStream_t stream) {
  const float* cls = (const float*)d_in[0];   // (32,1,384,384) f32
  const float* reg = (const float*)d_in[1];   // (32,4,384,384) f32
  float* out = (float*)d_out;                 // 160000 (out) + 32000 (keep) f32

  uint8_t* ws = (uint8_t*)d_ws;
  u32* pcnt = (u32*)(ws + PCNT_OFF);
  u64* pcand = (u64*)(ws + PCAND_OFF);
  float4* pbox = (float4*)(ws + PBOX_OFF);

  scan_kernel<<<dim3(NBLK, NIMG), 256, 0, stream>>>(cls, reg, pcnt, pcand, pbox);
  fused_kernel<<<NIMG, 1024, 0, stream>>>(cls, reg, pcnt, pcand, pbox, out);
}